// Round 7
// baseline (94.975 us; speedup 1.0000x reference)
//
#include <hip/hip_runtime.h>
#include <hip/hip_bf16.h>
#include <hip/hip_fp16.h>
#include <math.h>

#define BB   8
#define DD   1024

typedef short bh8 __attribute__((ext_vector_type(8)));
typedef float f32x4 __attribute__((ext_vector_type(4)));
typedef _Float16 h2f __attribute__((ext_vector_type(2)));

__device__ __forceinline__ ushort f2bf(float f) {
    uint u = __builtin_bit_cast(uint, f);
    u += 0x7fffu + ((u >> 16) & 1u);
    return (ushort)(u >> 16);
}
__device__ __forceinline__ float asf(uint u)  { return __builtin_bit_cast(float, u); }
__device__ __forceinline__ float bflo(uint u) { return __builtin_bit_cast(float, u << 16); }
__device__ __forceinline__ float bfhi(uint u) { return __builtin_bit_cast(float, u & 0xffff0000u); }
__device__ __forceinline__ uint  pkh(float a, float b) {
    return __builtin_bit_cast(uint, __builtin_amdgcn_cvt_pkrtz(a, b));
}
__device__ __forceinline__ h2f ash2f(uint u) { return __builtin_bit_cast(h2f, u); }

#if __has_builtin(__builtin_amdgcn_fdot2)
__device__ __forceinline__ float fdot2h(h2f a, h2f b, float c) {
    return __builtin_amdgcn_fdot2(a, b, c, false);
}
#else
__device__ __forceinline__ float fdot2h(h2f a, h2f b, float c) {
    return fmaf((float)a.x, (float)b.x, fmaf((float)a.y, (float)b.y, c));
}
#endif

// hardware packed f32->bf16 RTNE (no builtin on gfx950; asm per guide recipe)
__device__ __forceinline__ uint cvtpk_bf16(float a, float b) {
    uint r;
    asm("v_cvt_pk_bf16_f32 %0, %1, %2" : "=v"(r) : "v"(a), "v"(b));
    return r;
}
__device__ __forceinline__ ushort cvt1_bf16(float a) {
    uint r;
    asm("v_cvt_pk_bf16_f32 %0, %1, %2" : "=v"(r) : "v"(a), "v"(a));
    return (ushort)r;
}

// overflow-safe tanh-form gelu via exp2 + rcp
__device__ __forceinline__ float gelu_fast(float x) {
    float x2 = x * x;
#if __has_builtin(__builtin_amdgcn_exp2f)
    float e = __builtin_amdgcn_exp2f(x * fmaf(x2, -0.20588652f, -2.3022082f));
#else
    float e = __expf(-(1.5957691216f * x + 0.14270963f * x * x2));
#endif
    return x * __builtin_amdgcn_rcpf(1.0f + e);
}
__device__ __forceinline__ float sig63(float v) {
    return 63.0f * __builtin_amdgcn_rcpf(1.0f + __expf(-v));
}

// ---------------------------------------------------------------------------
// kT: ALL weight preprocessing (3-way split w_cat + proj/mlp fragment packs).
// ---------------------------------------------------------------------------
__global__ __launch_bounds__(256) void kT_pack(
    const float* __restrict__ w_idx, const float* __restrict__ w_mask,
    const float* __restrict__ w_proj, const float* __restrict__ w1,
    const float* __restrict__ w2,
    ushort* __restrict__ catPh, ushort* __restrict__ catPm,
    ushort* __restrict__ catPl,
    ushort* __restrict__ w_projP, ushort* __restrict__ w1P,
    ushort* __restrict__ w2P)
{
    int bid = blockIdx.x, t = threadIdx.x;
    if (bid < 24) {
        int gid = bid * 256 + t;                  // [0,6144)
        int l = gid & 63, ks = (gid >> 6) & 7, nt = gid >> 9;
        int n = nt * 16 + (l & 15);
        int kbase = ks * 32 + ((l >> 4) << 3);
        const float* src = (n < 64) ? (w_idx + (size_t)n * 256)
                                    : (w_mask + (size_t)(n - 64) * 256);
        ushort* dh = catPh + (size_t)gid * 8;
        ushort* dm = catPm + (size_t)gid * 8;
        ushort* dl = catPl + (size_t)gid * 8;
        #pragma unroll
        for (int j = 0; j < 8; ++j) {
            float v = src[kbase + j];
            ushort h = f2bf(v);
            float hf = __builtin_bit_cast(float, (uint)h << 16);
            float r1 = v - hf;
            ushort m = f2bf(r1); float mf = __builtin_bit_cast(float, (uint)m << 16);
            ushort lo = f2bf(r1 - mf);
            dh[j] = h; dm[j] = m; dl[j] = lo;
        }
    } else if (bid < 28) {               // w_proj (128,64): B[k=c][n=dch]
        int g = (bid - 24) * 256 + t;    // [0,1024)
        int nt = g >> 7, ks = (g >> 6) & 1, l = g & 63;
        int n = nt * 16 + (l & 15), k0 = ks * 32 + (l >> 4) * 8;
        ushort* dst = w_projP + (size_t)g * 8;
        #pragma unroll
        for (int j = 0; j < 8; ++j) dst[j] = f2bf(w_proj[n * 64 + k0 + j]);
    } else if (bid < 60) {               // w_mlp1 (512,128): B[k][n]
        int g = (bid - 28) * 256 + t;    // [0,8192)
        int nt = g >> 8, ks = (g >> 6) & 3, l = g & 63;
        int n = nt * 16 + (l & 15), k0 = ks * 32 + (l >> 4) * 8;
        ushort* dst = w1P + (size_t)g * 8;
        #pragma unroll
        for (int j = 0; j < 8; ++j) dst[j] = f2bf(w1[n * 128 + k0 + j]);
    } else {                             // w_mlp2 (128,512): B[k][n]
        int g = (bid - 60) * 256 + t;    // [0,8192)
        int nt = g >> 10, ks = (g >> 6) & 15, l = g & 63;
        int n = nt * 16 + (l & 15), k0 = ks * 32 + (l >> 4) * 8;
        ushort* dst = w2P + (size_t)g * 8;
        #pragma unroll
        for (int j = 0; j < 8; ++j) dst[j] = f2bf(w2[n * 512 + k0 + j]);
    }
}

// ---------------------------------------------------------------------------
// k01: fat kernel.
//  blocks [0,4096)    : k1 texture coefficients, 8 channels/block (13KB LDS
//                       -> 8 blocks/CU), bid = h*64 + b*8 + chunk so all h of
//                       a (b,chunk) column share an XCD (h-1 row L2-warm).
//  blocks [4096,4608) : k0 via MFMA (3-way bf16 split) + meta/softmax.
// ---------------------------------------------------------------------------
__global__ __launch_bounds__(256) void k01(
    const float* __restrict__ x,
    const ushort* __restrict__ catPh, const ushort* __restrict__ catPm,
    const ushort* __restrict__ catPl,
    const float* __restrict__ b_idx, const float* __restrict__ b_mask,
    float* __restrict__ maskw, uint* __restrict__ meta,
    const float* __restrict__ I, const float* __restrict__ IX,
    const float* __restrict__ IY, const float* __restrict__ IT,
    uint4* __restrict__ T1, ushort* __restrict__ T2)
{
    __shared__ __align__(16) float sf[3264];      // 13056 B
    int t = threadIdx.x;
    int bid = blockIdx.x;

    if (bid >= 4096) {
        // ---------------- k0: coords + mask via MFMA ----------------
        float* sOut = sf;                          // [16][193] = 3088 f
        size_t rowbase = (size_t)(bid - 4096) * 16;
        int w = t >> 6, l = t & 63;

        f32x4 acc[3];
        acc[0] = (f32x4){0.f,0.f,0.f,0.f};
        acc[1] = (f32x4){0.f,0.f,0.f,0.f};
        acc[2] = (f32x4){0.f,0.f,0.f,0.f};
        const float* xr = x + (rowbase + (size_t)(l & 15)) * 256 + ((l >> 4) << 3);

        #pragma unroll
        for (int half = 0; half < 2; ++half) {
            bh8 Ah[4], Am[4], Al[4];
            #pragma unroll
            for (int k4 = 0; k4 < 4; ++k4) {
                int ks = half * 4 + k4;
                float4 v0 = *(const float4*)(xr + ks * 32);
                float4 v1 = *(const float4*)(xr + ks * 32 + 4);
                uint4 uh, um, ul;
                uh.x = cvtpk_bf16(v0.x, v0.y);
                uh.y = cvtpk_bf16(v0.z, v0.w);
                uh.z = cvtpk_bf16(v1.x, v1.y);
                uh.w = cvtpk_bf16(v1.z, v1.w);
                float r0a = v0.x - bflo(uh.x), r0b = v0.y - bfhi(uh.x);
                float r0c = v0.z - bflo(uh.y), r0d = v0.w - bfhi(uh.y);
                float r1a = v1.x - bflo(uh.z), r1b = v1.y - bfhi(uh.z);
                float r1c = v1.z - bflo(uh.w), r1d = v1.w - bfhi(uh.w);
                um.x = cvtpk_bf16(r0a, r0b);
                um.y = cvtpk_bf16(r0c, r0d);
                um.z = cvtpk_bf16(r1a, r1b);
                um.w = cvtpk_bf16(r1c, r1d);
                ul.x = cvtpk_bf16(r0a - bflo(um.x), r0b - bfhi(um.x));
                ul.y = cvtpk_bf16(r0c - bflo(um.y), r0d - bfhi(um.y));
                ul.z = cvtpk_bf16(r1a - bflo(um.z), r1b - bfhi(um.z));
                ul.w = cvtpk_bf16(r1c - bflo(um.w), r1d - bfhi(um.w));
                Ah[k4] = __builtin_bit_cast(bh8, uh);
                Am[k4] = __builtin_bit_cast(bh8, um);
                Al[k4] = __builtin_bit_cast(bh8, ul);
            }
            #pragma unroll
            for (int ntl = 0; ntl < 3; ++ntl) {
                int nt = w * 3 + ntl;
                #pragma unroll
                for (int k4 = 0; k4 < 4; ++k4) {
                    int ks = half * 4 + k4;
                    size_t fo = ((size_t)(nt * 8 + ks) * 64 + l) * 8;
                    bh8 bh = *(const bh8*)(catPh + fo);
                    bh8 bm = *(const bh8*)(catPm + fo);
                    bh8 bl = *(const bh8*)(catPl + fo);
                    acc[ntl] = __builtin_amdgcn_mfma_f32_16x16x32_bf16(Ah[k4], bh, acc[ntl], 0, 0, 0);
                    acc[ntl] = __builtin_amdgcn_mfma_f32_16x16x32_bf16(Ah[k4], bm, acc[ntl], 0, 0, 0);
                    acc[ntl] = __builtin_amdgcn_mfma_f32_16x16x32_bf16(Am[k4], bh, acc[ntl], 0, 0, 0);
                    acc[ntl] = __builtin_amdgcn_mfma_f32_16x16x32_bf16(Ah[k4], bl, acc[ntl], 0, 0, 0);
                    acc[ntl] = __builtin_amdgcn_mfma_f32_16x16x32_bf16(Al[k4], bh, acc[ntl], 0, 0, 0);
                    acc[ntl] = __builtin_amdgcn_mfma_f32_16x16x32_bf16(Am[k4], bm, acc[ntl], 0, 0, 0);
                }
            }
        }
        {
            int r0 = (l >> 4) * 4, cbase = w * 48 + (l & 15);
            #pragma unroll
            for (int ntl = 0; ntl < 3; ++ntl)
                #pragma unroll
                for (int reg = 0; reg < 4; ++reg)
                    sOut[(r0 + reg) * 193 + cbase + ntl * 16] = acc[ntl][reg];
        }
        __syncthreads();

        // meta epilogue: 16 rows x 16 units = 256 threads
        {
            int row = t >> 4, u = t & 15, br = u >> 3, nr = u & 7;
            const float* so = sOut + row * 193;
            int c0 = br * 32 + nr * 4;
            float x1 = sig63(so[c0 + 0] + b_idx[c0 + 0]);
            float y1 = sig63(so[c0 + 1] + b_idx[c0 + 1]);
            float x2 = sig63(so[c0 + 2] + b_idx[c0 + 2]);
            float y2 = sig63(so[c0 + 3] + b_idx[c0 + 3]);
            int X1 = (int)ceilf(x1); X1 = X1 < 1 ? 1 : (X1 > 63 ? 63 : X1);
            int X2 = (int)ceilf(x2); X2 = X2 < 1 ? 1 : (X2 > 63 ? 63 : X2);
            int Y1 = (int)ceilf(y1); Y1 = Y1 < 1 ? 1 : (Y1 > 63 ? 63 : Y1);
            int Y2 = (int)ceilf(y2); Y2 = Y2 < 1 ? 1 : (Y2 > 63 ? 63 : Y2);
            float dxa = (float)X1 - x1, dxb = (float)X2 - x2;
            float dya = (float)Y1 - y1, dyb = (float)Y2 - y2;
            int   Xc[4] = {X2, X1, X2, X1};
            int   Yc[4] = {Y2, Y2, Y1, Y1};
            float sg[4] = {1.f, -1.f, -1.f, 1.f};
            float dxc[4] = {dxb, dxa, dxb, dxa};
            float dyc[4] = {dyb, dyb, dya, dya};
            uint* mr = meta + (((rowbase + row) * 16) + (size_t)u) * 32;
            #pragma unroll
            for (int c = 0; c < 4; ++c) {
                uint pt = (uint)(Xc[c] * 64 + Yc[c]);
                float s = sg[c], dx = dxc[c], dy = dyc[c];
                float dx2 = dx * dx, dy2 = dy * dy;
                uint4 wa, wb;
                wa.x = pt * 1024u;
                wa.y = pt * 128u;
                wa.z = pkh(s, s * dy);
                wa.w = pkh(s * dy2, s * dx);
                wb.x = pkh(s * dx2, s * dx * dy);
                wb.y = pkh(s * dx * dy2, s * dx2 * dy);
                wb.z = __builtin_bit_cast(uint, s * dx2 * dy2);
                wb.w = 0u;
                *(uint4*)(mr + c * 8 + 0) = wa;
                *(uint4*)(mr + c * 8 + 4) = wb;
            }
        }
        // softmax epilogue: 16 rows x (2 br x 8 g) = 256 threads
        {
            int row = t >> 4, br = (t >> 3) & 1, g = t & 7;
            const float* so = sOut + row * 193 + 64;
            float lg[8];
            float mx = -1e30f;
            #pragma unroll
            for (int nr = 0; nr < 8; ++nr) {
                int idx = br * 64 + nr * 8 + g;
                lg[nr] = so[idx] + b_mask[idx];
                mx = fmaxf(mx, lg[nr]);
            }
            float s = 0.f;
            #pragma unroll
            for (int nr = 0; nr < 8; ++nr) { lg[nr] = __expf(lg[nr] - mx); s += lg[nr]; }
            float inv = __builtin_amdgcn_rcpf(s);
            #pragma unroll
            for (int nr = 0; nr < 8; ++nr)
                maskw[(rowbase + row) * 128 + br * 64 + nr * 8 + g] = lg[nr] * inv;
        }
    } else {
        // ---------------- k1: 9-coeff texture, 8 channels/block -------------
        // LDS float offsets: tI=0, tIp=544, tX=1088, tY=1632, tYp=2176, tT=2720
        int chunk = bid & 7, b = (bid >> 3) & 7, h = bid >> 6;
        int hp = h > 0 ? h - 1 : 0;
        int cb = chunk * 8;
        size_t inb  = (size_t)b * 262144 + (size_t)h  * 64;
        size_t inbp = (size_t)b * 262144 + (size_t)hp * 64;

        {
            int half = t >> 7;                 // 0 or 1
            int pos = t & 127, c = pos >> 4, w4 = (pos & 15) << 2;
            size_t o = (size_t)(cb + c) * 4096 + w4;
            int so = c * 68 + w4;
            int base = half ? 544 : 0;
            const float* pA = half ? (I  + inbp) : (I  + inb);
            const float* pB = half ? (IY + inb)  : (IX + inb);
            const float* pC = half ? (IT + inb)  : (IY + inbp);
            *(float4*)(sf + base + so)               = *(const float4*)(pA + o);
            *(float4*)(sf + 1088 + base + so)        = *(const float4*)(pB + o);
            *(float4*)(sf + 2176 + base + so)        = *(const float4*)(pC + o);
        }
        __syncthreads();

        #pragma unroll
        for (int i = 0; i < 2; ++i) {
            int idx = i * 256 + t; int w = idx >> 3, c = idx & 7;
            int wm = w > 0 ? w - 1 : 0;
            int rb = c * 68;
            float I00 = sf[rb + w],        I0m = sf[rb + wm];
            float Im0 = sf[544 + rb + w],  Imm = sf[544 + rb + wm];
            float E1  = sf[1088 + rb + w]  - 0.5f * I00;
            float E1m = sf[1088 + rb + wm] - 0.5f * I0m;
            float E2  = sf[1632 + rb + w]  - 0.5f * I00;
            float E2m = sf[2176 + rb + w]  - 0.5f * Im0;
            float v0 = sf[2720 + rb + w];
            float v1 = -E1;
            float v2 = 0.5f * (E1 - E1m);
            float v3 = -E2;
            float v4 = 0.5f * (E2 - E2m);
            float v5 = I00;
            float v6 = 0.5f * (I0m - I00);
            float v7 = 0.5f * (Im0 - I00);
            float v8 = 0.25f * ((Imm - I0m) - (Im0 - I00));
            size_t pt = (((size_t)b * 4096) + (size_t)h * 64 + w) * 64 + (cb + c);
            uint4 o4;
            o4.x = pkh(v0, v1);
            o4.y = pkh(v2, v3);
            o4.z = pkh(v4, v5);
            o4.w = pkh(v6, v7);
            T1[pt] = o4;
            T2[pt] = (ushort)(pkh(v8, 0.f) & 0xffffu);
        }
    }
}

// ---------------------------------------------------------------------------
// k2: fused sampling + rects GEMM + gelu + mask-sum + LN1.  (round-5 proven
// structure: one d-tile/block, depth-2 gather pipeline, SGPR offsets)
// ---------------------------------------------------------------------------
__global__ __launch_bounds__(256) void k2_rects(
    const uint4* __restrict__ T1, const ushort* __restrict__ T2,
    const uint* __restrict__ meta,
    const ushort* __restrict__ w_projP, const float* __restrict__ b_proj,
    const float* __restrict__ maskw, const float* __restrict__ g1,
    const float* __restrict__ beta1, float* __restrict__ mid)
{
    __shared__ __align__(16) uint meta_lds[16][32];
    __shared__ __align__(16) float S_lds[16][68];
    __shared__ float mrow[128];
    __shared__ float outr[2][128];
    int bid = blockIdx.x;
    int b = bid & 7, d = bid >> 3;
    int t = threadIdx.x, w = t >> 6, l = t & 63;
    size_t tile = (size_t)b * DD + d;
    if (t < 128) {
        uint4 mv = *(const uint4*)(meta + tile * 512 + (size_t)t * 4);
        *(uint4*)(&meta_lds[0][0] + t * 4) = mv;
    }
    if (t >= 128) mrow[t - 128] = maskw[tile * 128 + (t - 128)];

    bh8 bf[2][2];
    #pragma unroll
    for (int ni = 0; ni < 2; ++ni) {
        int nt = w * 2 + ni;
        #pragma unroll
        for (int ks = 0; ks < 2; ++ks)
            bf[ni][ks] = *(const bh8*)(w_projP + ((size_t)(nt * 2 + ks) * 64 + l) * 8);
    }
    __syncthreads();
    const char* t1b = ((const char*)T1) + ((size_t)b << 22) + (size_t)(l * 16);
    const char* t2b = ((const char*)T2) + ((size_t)b << 19) + (size_t)(l * 2);

    int m0 = w * 4;
    uint4 q[2][4]; ushort e8[2][4];
    #pragma unroll
    for (int g = 0; g < 2; ++g) {
        #pragma unroll
        for (int c = 0; c < 4; ++c) {
            uint o1 = __builtin_amdgcn_readfirstlane(meta_lds[m0 + g][c * 8 + 0]);
            uint o2 = __builtin_amdgcn_readfirstlane(meta_lds[m0 + g][c * 8 + 1]);
            q[g][c]  = *(const uint4*)(t1b + o1);
            e8[g][c] = *(const ushort*)(t2b + o2);
        }
    }
    #pragma unroll
    for (int rr = 0; rr < 4; ++rr) {
        int m = m0 + rr;
        int cur = rr & 1;
        uint4 qc[4]; ushort ec[4];
        #pragma unroll
        for (int c = 0; c < 4; ++c) { qc[c] = q[cur][c]; ec[c] = e8[cur][c]; }
        if (rr < 2) {
            int mn = m + 2;
            #pragma unroll
            for (int c = 0; c < 4; ++c) {
                uint o1 = __builtin_amdgcn_readfirstlane(meta_lds[mn][c * 8 + 0]);
                uint o2 = __builtin_amdgcn_readfirstlane(meta_lds[mn][c * 8 + 1]);
                q[cur][c]  = *(const uint4*)(t1b + o1);
                e8[cur][c] = *(const ushort*)(t2b + o2);
            }
        }
        float acc0 = 0.f, acc1 = 0.f;
        #pragma unroll
        for (int c = 0; c < 4; ++c) {
            uint cz = meta_lds[m][c * 8 + 2], cw = meta_lds[m][c * 8 + 3];
            uint bx = meta_lds[m][c * 8 + 4], by = meta_lds[m][c * 8 + 5];
            float bz = asf(meta_lds[m][c * 8 + 6]);
            float ev = __half2float(__builtin_bit_cast(__half, ec[c]));
            float cv = bz * ev;
            cv = fdot2h(ash2f(by), ash2f(qc[c].w), cv);
            cv = fdot2h(ash2f(bx), ash2f(qc[c].z), cv);
            cv = fdot2h(ash2f(cw), ash2f(qc[c].y), cv);
            cv = fdot2h(ash2f(cz), ash2f(qc[c].x), cv);
            if (c & 1) acc1 += cv; else acc0 += cv;
        }
        S_lds[m][l] = acc0 + acc1;
    }
    __syncthreads();

    int am = l & 15, q2 = l >> 4;
    bh8 a0, a1;
    {
        float4 va = *(const float4*)&S_lds[am][q2 * 8];
        float4 vb = *(const float4*)&S_lds[am][q2 * 8 + 4];
        uint4 ua;
        ua.x = cvtpk_bf16(va.x, va.y);
        ua.y = cvtpk_bf16(va.z, va.w);
        ua.z = cvtpk_bf16(vb.x, vb.y);
        ua.w = cvtpk_bf16(vb.z, vb.w);
        a0 = __builtin_bit_cast(bh8, ua);
        float4 vc = *(const float4*)&S_lds[am][32 + q2 * 8];
        float4 vd = *(const float4*)&S_lds[am][32 + q2 * 8 + 4];
        uint4 ub;
        ub.x = cvtpk_bf16(vc.x, vc.y);
        ub.y = cvtpk_bf16(vc.z, vc.w);
        ub.z = cvtpk_bf16(vd.x, vd.y);
        ub.w = cvtpk_bf16(vd.z, vd.w);
        a1 = __builtin_bit_cast(bh8, ub);
    }
    f32x4 cc[2];
    cc[0] = (f32x4){0.f, 0.f, 0.f, 0.f};
    cc[1] = (f32x4){0.f, 0.f, 0.f, 0.f};
    cc[0] = __builtin_amdgcn_mfma_f32_16x16x32_bf16(a0, bf[0][0], cc[0], 0, 0, 0);
    cc[0] = __builtin_amdgcn_mfma_f32_16x16x32_bf16(a1, bf[0][1], cc[0], 0, 0, 0);
    cc[1] = __builtin_amdgcn_mfma_f32_16x16x32_bf16(a0, bf[1][0], cc[1], 0, 0, 0);
    cc[1] = __builtin_amdgcn_mfma_f32_16x16x32_bf16(a1, bf[1][1], cc[1], 0, 0, 0);

    int cl = l & 15;
    #pragma unroll
    for (int ni = 0; ni < 2; ++ni) {
        int nt = w * 2 + ni;
        int col = nt * 16 + cl;
        float bpv = b_proj[col];
        float p = 0.f;
        #pragma unroll
        for (int reg = 0; reg < 4; ++reg) {
            int r = q2 * 4 + reg;
            float v = cc[ni][reg] + bpv;
            p += gelu_fast(v) * mrow[(r >> 3) * 64 + (r & 7) * 8 + nt];
        }
        p += __shfl_xor(p, 16, 64);
        if (q2 == 0) outr[0][col] = p;
        else if (q2 == 2) outr[1][col] = p;
    }
    __syncthreads();

    if (w < 2) {
        float v0 = outr[w][l], v1 = outr[w][l + 64];
        float s = v0 + v1, sq = v0 * v0 + v1 * v1;
        #pragma unroll
        for (int mm = 32; mm > 0; mm >>= 1) {
            s  += __shfl_xor(s, mm, 64);
            sq += __shfl_xor(sq, mm, 64);
        }
        float mu  = s * (1.0f / 128.0f);
        float var = sq * (1.0f / 128.0f) - mu * mu;
        float rs  = rsqrtf(var + 1e-5f);
        size_t ob = (tile * 2 + w) * 128;
        mid[ob + l]      = (v0 - mu) * rs * g1[l]      + beta1[l];
        mid[ob + l + 64] = (v1 - mu) * rs * g1[l + 64] + beta1[l + 64];
    }
}

// ---------------------------------------------------------------------------
// k4: MLP 128->512(gelu)->128 via MFMA, 16 rows/block, + LN2 + residual.
// ---------------------------------------------------------------------------
__global__ __launch_bounds__(256) void k4_mlp(
    const float* __restrict__ mid, const ushort* __restrict__ w1P,
    const float* __restrict__ b1, const ushort* __restrict__ w2P,
    const float* __restrict__ b2, const float* __restrict__ g2,
    const float* __restrict__ beta2, float* __restrict__ outp)
{
    __shared__ float xr[16][132];
    __shared__ __align__(16) ushort Af[4][64][8];
    __shared__ __align__(16) ushort H[16][520];
    __shared__ float oo[16][128];
    __shared__ float b1s[512];
    __shared__ float b2s[128], g2s[128], bt2s[128];
    int t = threadIdx.x, w = t >> 6, l = t & 63;
    int bid = blockIdx.x;
    int mt = (bid & 7) * 128 + (bid >> 3);   // XCD-local by batch
    size_t rowbase = (size_t)mt * 16;

    {
        const float4* mg = (const float4*)(mid + rowbase * 128);
        #pragma unroll
        for (int i4 = 0; i4 < 2; ++i4) {
            int i = i4 * 256 + t;
            float4 v = mg[i];
            *(float4*)(&xr[i >> 5][(i & 31) * 4]) = v;
        }
    }
    for (int i = t; i < 512; i += 256) b1s[i] = b1[i];
    if (t < 128) { b2s[t] = b2[t]; g2s[t] = g2[t]; bt2s[t] = beta2[t]; }
    __syncthreads();

    {
        int ks = t >> 6, m = l & 15, c0 = ks * 32 + (l >> 4) * 8;
        uint* dst = (uint*)&Af[ks][l][0];
        #pragma unroll
        for (int j = 0; j < 4; ++j)
            dst[j] = cvtpk_bf16(xr[m][c0 + 2 * j], xr[m][c0 + 2 * j + 1]);
    }
    __syncthreads();

    f32x4 c1[8];
    #pragma unroll
    for (int i = 0; i < 8; ++i) c1[i] = (f32x4){0.f, 0.f, 0.f, 0.f};
    bh8 a[4];
    #pragma unroll
    for (int ks = 0; ks < 4; ++ks) a[ks] = *(const bh8*)&Af[ks][l][0];
    #pragma unroll
    for (int ni = 0; ni < 8; ++ni) {
        int nt = w * 8 + ni;
        #pragma unroll
        for (int ks = 0; ks < 4; ++ks) {
            bh8 bfr = *(const bh8*)(w1P + ((size_t)(nt * 4 + ks) * 64 + l) * 8);
            c1[ni] = __builtin_amdgcn_mfma_f32_16x16x32_bf16(a[ks], bfr, c1[ni], 0, 0, 0);
        }
    }
    #pragma unroll
    for (int ni = 0; ni < 8; ++ni) {
        int nt = w * 8 + ni;
        int col = nt * 16 + (l & 15);
        int r0 = (l >> 4) * 4;
        #pragma unroll
        for (int reg = 0; reg < 4; ++reg)
            H[r0 + reg][col] = cvt1_bf16(gelu_fast(c1[ni][reg] + b1s[col]));
    }
    __syncthreads();

    f32x4 c2[2];
    c2[0] = (f32x4){0.f, 0.f, 0.f, 0.f};
    c2[1] = (f32x4){0.f, 0.f, 0.f, 0.f};
    const char* hb = (const char*)&H[0][0];
    #pragma unroll
    for (int ks2 = 0; ks2 < 16; ++ks2) {
        bh8 af = *(const bh8*)(hb + (l & 15) * 1040 + ks2 * 64 + (l >> 4) * 16);
        #pragma unroll
        for (int i = 0; i < 2; ++i) {
            int nt2 = w * 2 + i;
            bh8 bfr = *(const bh8*)(w2P + ((size_t)(nt2 * 16 + ks2) * 64 + l) * 8);
            c2[i] = __builtin_amdgcn_mfma_f32_16x16x32_bf16(af, bfr, c2[i], 0, 0, 0);
        }
    }
    #pragma unroll
    for (int i = 0; i < 2; ++i) {
        int col = (w * 2 + i) * 16 + (l & 15);
        int r0 = (l >> 4) * 4;
        #pragma unroll
        for (int reg = 0; reg < 4; ++reg) oo[r0 + reg][col] = c2[i][reg] + b2s[col];
    }
    __syncthreads();

    #pragma unroll
    for (int rr = 0; rr < 4; ++rr) {
        int r = w * 4 + rr;
        float v0 = oo[r][l], v1 = oo[r][l + 64];
        float s = v0 + v1, sq = v0 * v0 + v1 * v1;
        #pragma unroll
        for (int m = 32; m > 0; m >>= 1) {
            s  += __shfl_xor(s, m, 64);
            sq += __shfl_xor(sq, m, 64);
        }
        float mu  = s * (1.0f / 128.0f);
        float var = sq * (1.0f / 128.0f) - mu * mu;
        float rs  = rsqrtf(var + 1e-5f);
        size_t ob = (rowbase + r) * 128;
        outp[ob + l]      = (v0 - mu) * rs * g2s[l]      + bt2s[l]      + xr[r][l];
        outp[ob + l + 64] = (v1 - mu) * rs * g2s[l + 64] + bt2s[l + 64] + xr[r][l + 64];
    }
}

// ---------------------------------------------------------------------------
extern "C" void kernel_launch(void* const* d_in, const int* in_sizes, int n_in,
                              void* d_out, int out_size, void* d_ws, size_t ws_size,
                              hipStream_t stream) {
    const float* x      = (const float*)d_in[0];
    const float* I      = (const float*)d_in[1];
    const float* IX     = (const float*)d_in[2];
    const float* IY     = (const float*)d_in[3];
    const float* IT     = (const float*)d_in[4];
    const float* w_idx  = (const float*)d_in[5];
    const float* b_idx  = (const float*)d_in[6];
    const float* w_proj = (const float*)d_in[7];
    const float* b_proj = (const float*)d_in[8];
    const float* w_mask = (const float*)d_in[9];
    const float* b_mask = (const float*)d_in[10];
    const float* g1     = (const float*)d_in[11];
    const float* beta1  = (const float*)d_in[12];
    const float* w_mlp1 = (const float*)d_in[13];
    const float* b_mlp1 = (const float*)d_in[14];
    const float* w_mlp2 = (const float*)d_in[15];
    const float* b_mlp2 = (const float*)d_in[16];
    const float* g2     = (const float*)d_in[17];
    const float* beta2  = (const float*)d_in[18];
    float* out = (float*)d_out;

    float* ws = (float*)d_ws;
    ushort* catPh  = (ushort*)ws;                  // 49152 us -> 24576 f
    ushort* catPm  = (ushort*)(ws + 24576);        // 49152 us -> 49152 f
    ushort* catPl  = (ushort*)(ws + 49152);        // 49152 us -> 73728 f
    ushort* w_projP = (ushort*)(ws + 73728);       // 8192 us  -> 77824
    ushort* w1P     = (ushort*)(ws + 77824);       // 65536 us -> 110592
    ushort* w2P     = (ushort*)(ws + 110592);      // 65536 us -> 143360
    float*  maskw   = ws + 143360;                 // 1048576 f -> 1191936
    uint*   meta    = (uint*)(ws + 1191936);       // 4194304 w -> 5386240
    uint4*  T1      = (uint4*)(ws + 5386240);      // 2097152 u4 -> 13774848
    ushort* T2      = (ushort*)(ws + 13774848);    // 2097152 us -> 14823424 (59MB)

    kT_pack<<<92, 256, 0, stream>>>(w_idx, w_mask, w_proj, w_mlp1, w_mlp2,
                                    catPh, catPm, catPl, w_projP, w1P, w2P);
    k01<<<4608, 256, 0, stream>>>(x, catPh, catPm, catPl, b_idx, b_mask,
                                  maskw, meta, I, IX, IY, IT, T1, T2);
    k2_rects<<<8192, 256, 0, stream>>>(T1, T2, meta, w_projP, b_proj, maskw,
                                       g1, beta1, out);
    k4_mlp<<<1024, 256, 0, stream>>>(out, w1P, b_mlp1, w2P, b_mlp2, g2, beta2, out);
}

// Round 8
// 93.819 us; speedup vs baseline: 1.0123x; 1.0123x over previous
//
#include <hip/hip_runtime.h>
#include <hip/hip_bf16.h>
#include <hip/hip_fp16.h>
#include <math.h>

#define BB   8
#define DD   1024

typedef short bh8 __attribute__((ext_vector_type(8)));
typedef float f32x4 __attribute__((ext_vector_type(4)));
typedef _Float16 h2f __attribute__((ext_vector_type(2)));

__device__ __forceinline__ ushort f2bf(float f) {
    uint u = __builtin_bit_cast(uint, f);
    u += 0x7fffu + ((u >> 16) & 1u);
    return (ushort)(u >> 16);
}
__device__ __forceinline__ float asf(uint u)  { return __builtin_bit_cast(float, u); }
__device__ __forceinline__ float bflo(uint u) { return __builtin_bit_cast(float, u << 16); }
__device__ __forceinline__ float bfhi(uint u) { return __builtin_bit_cast(float, u & 0xffff0000u); }
__device__ __forceinline__ uint  pkh(float a, float b) {
    return __builtin_bit_cast(uint, __builtin_amdgcn_cvt_pkrtz(a, b));
}
__device__ __forceinline__ h2f ash2f(uint u) { return __builtin_bit_cast(h2f, u); }

#if __has_builtin(__builtin_amdgcn_fdot2)
__device__ __forceinline__ float fdot2h(h2f a, h2f b, float c) {
    return __builtin_amdgcn_fdot2(a, b, c, false);
}
#else
__device__ __forceinline__ float fdot2h(h2f a, h2f b, float c) {
    return fmaf((float)a.x, (float)b.x, fmaf((float)a.y, (float)b.y, c));
}
#endif

// hardware packed f32->bf16 RTNE (no builtin on gfx950; asm per guide recipe)
__device__ __forceinline__ uint cvtpk_bf16(float a, float b) {
    uint r;
    asm("v_cvt_pk_bf16_f32 %0, %1, %2" : "=v"(r) : "v"(a), "v"(b));
    return r;
}
__device__ __forceinline__ ushort cvt1_bf16(float a) {
    uint r;
    asm("v_cvt_pk_bf16_f32 %0, %1, %2" : "=v"(r) : "v"(a), "v"(a));
    return (ushort)r;
}

// overflow-safe tanh-form gelu via exp2 + rcp
__device__ __forceinline__ float gelu_fast(float x) {
    float x2 = x * x;
#if __has_builtin(__builtin_amdgcn_exp2f)
    float e = __builtin_amdgcn_exp2f(x * fmaf(x2, -0.20588652f, -2.3022082f));
#else
    float e = __expf(-(1.5957691216f * x + 0.14270963f * x * x2));
#endif
    return x * __builtin_amdgcn_rcpf(1.0f + e);
}
__device__ __forceinline__ float sig63(float v) {
    return 63.0f * __builtin_amdgcn_rcpf(1.0f + __expf(-v));
}

// ---------------------------------------------------------------------------
// kT: ALL weight preprocessing (3-way split w_cat + proj/mlp fragment packs).
// ---------------------------------------------------------------------------
__global__ __launch_bounds__(256) void kT_pack(
    const float* __restrict__ w_idx, const float* __restrict__ w_mask,
    const float* __restrict__ w_proj, const float* __restrict__ w1,
    const float* __restrict__ w2,
    ushort* __restrict__ catPh, ushort* __restrict__ catPm,
    ushort* __restrict__ catPl,
    ushort* __restrict__ w_projP, ushort* __restrict__ w1P,
    ushort* __restrict__ w2P)
{
    int bid = blockIdx.x, t = threadIdx.x;
    if (bid < 24) {
        int gid = bid * 256 + t;                  // [0,6144)
        int l = gid & 63, ks = (gid >> 6) & 7, nt = gid >> 9;
        int n = nt * 16 + (l & 15);
        int kbase = ks * 32 + ((l >> 4) << 3);
        const float* src = (n < 64) ? (w_idx + (size_t)n * 256)
                                    : (w_mask + (size_t)(n - 64) * 256);
        ushort* dh = catPh + (size_t)gid * 8;
        ushort* dm = catPm + (size_t)gid * 8;
        ushort* dl = catPl + (size_t)gid * 8;
        #pragma unroll
        for (int j = 0; j < 8; ++j) {
            float v = src[kbase + j];
            ushort h = f2bf(v);
            float hf = __builtin_bit_cast(float, (uint)h << 16);
            float r1 = v - hf;
            ushort m = f2bf(r1); float mf = __builtin_bit_cast(float, (uint)m << 16);
            ushort lo = f2bf(r1 - mf);
            dh[j] = h; dm[j] = m; dl[j] = lo;
        }
    } else if (bid < 28) {               // w_proj (128,64): B[k=c][n=dch]
        int g = (bid - 24) * 256 + t;    // [0,1024)
        int nt = g >> 7, ks = (g >> 6) & 1, l = g & 63;
        int n = nt * 16 + (l & 15), k0 = ks * 32 + (l >> 4) * 8;
        ushort* dst = w_projP + (size_t)g * 8;
        #pragma unroll
        for (int j = 0; j < 8; ++j) dst[j] = f2bf(w_proj[n * 64 + k0 + j]);
    } else if (bid < 60) {               // w_mlp1 (512,128): B[k][n]
        int g = (bid - 28) * 256 + t;    // [0,8192)
        int nt = g >> 8, ks = (g >> 6) & 3, l = g & 63;
        int n = nt * 16 + (l & 15), k0 = ks * 32 + (l >> 4) * 8;
        ushort* dst = w1P + (size_t)g * 8;
        #pragma unroll
        for (int j = 0; j < 8; ++j) dst[j] = f2bf(w1[n * 128 + k0 + j]);
    } else {                             // w_mlp2 (128,512): B[k][n]
        int g = (bid - 60) * 256 + t;    // [0,8192)
        int nt = g >> 10, ks = (g >> 6) & 15, l = g & 63;
        int n = nt * 16 + (l & 15), k0 = ks * 32 + (l >> 4) * 8;
        ushort* dst = w2P + (size_t)g * 8;
        #pragma unroll
        for (int j = 0; j < 8; ++j) dst[j] = f2bf(w2[n * 512 + k0 + j]);
    }
}

// ---------------------------------------------------------------------------
// k01: fat kernel.
//  blocks [0,2048)    : k1 texture coefficients — LDS-FREE streaming form.
//                       16-lane group per (b,c,h) row; 6 coalesced float4
//                       loads/thread; w-1 neighbors via __shfl_up(.,1,16);
//                       no barrier anywhere.
//  blocks [2048,2560) : k0 via MFMA (3-way bf16 split) + meta/softmax.
// ---------------------------------------------------------------------------
__global__ __launch_bounds__(256) void k01(
    const float* __restrict__ x,
    const ushort* __restrict__ catPh, const ushort* __restrict__ catPm,
    const ushort* __restrict__ catPl,
    const float* __restrict__ b_idx, const float* __restrict__ b_mask,
    float* __restrict__ maskw, uint* __restrict__ meta,
    const float* __restrict__ I, const float* __restrict__ IX,
    const float* __restrict__ IY, const float* __restrict__ IT,
    uint4* __restrict__ T1, ushort* __restrict__ T2)
{
    __shared__ __align__(16) float sf[3264];      // 13056 B (k0 path only)
    int t = threadIdx.x;
    int bid = blockIdx.x;

    if (bid >= 2048) {
        // ---------------- k0: coords + mask via MFMA ----------------
        float* sOut = sf;                          // [16][193] = 3088 f
        size_t rowbase = (size_t)(bid - 2048) * 16;
        int w = t >> 6, l = t & 63;

        f32x4 acc[3];
        acc[0] = (f32x4){0.f,0.f,0.f,0.f};
        acc[1] = (f32x4){0.f,0.f,0.f,0.f};
        acc[2] = (f32x4){0.f,0.f,0.f,0.f};
        const float* xr = x + (rowbase + (size_t)(l & 15)) * 256 + ((l >> 4) << 3);

        #pragma unroll
        for (int half = 0; half < 2; ++half) {
            bh8 Ah[4], Am[4], Al[4];
            #pragma unroll
            for (int k4 = 0; k4 < 4; ++k4) {
                int ks = half * 4 + k4;
                float4 v0 = *(const float4*)(xr + ks * 32);
                float4 v1 = *(const float4*)(xr + ks * 32 + 4);
                uint4 uh, um, ul;
                uh.x = cvtpk_bf16(v0.x, v0.y);
                uh.y = cvtpk_bf16(v0.z, v0.w);
                uh.z = cvtpk_bf16(v1.x, v1.y);
                uh.w = cvtpk_bf16(v1.z, v1.w);
                float r0a = v0.x - bflo(uh.x), r0b = v0.y - bfhi(uh.x);
                float r0c = v0.z - bflo(uh.y), r0d = v0.w - bfhi(uh.y);
                float r1a = v1.x - bflo(uh.z), r1b = v1.y - bfhi(uh.z);
                float r1c = v1.z - bflo(uh.w), r1d = v1.w - bfhi(uh.w);
                um.x = cvtpk_bf16(r0a, r0b);
                um.y = cvtpk_bf16(r0c, r0d);
                um.z = cvtpk_bf16(r1a, r1b);
                um.w = cvtpk_bf16(r1c, r1d);
                ul.x = cvtpk_bf16(r0a - bflo(um.x), r0b - bfhi(um.x));
                ul.y = cvtpk_bf16(r0c - bflo(um.y), r0d - bfhi(um.y));
                ul.z = cvtpk_bf16(r1a - bflo(um.z), r1b - bfhi(um.z));
                ul.w = cvtpk_bf16(r1c - bflo(um.w), r1d - bfhi(um.w));
                Ah[k4] = __builtin_bit_cast(bh8, uh);
                Am[k4] = __builtin_bit_cast(bh8, um);
                Al[k4] = __builtin_bit_cast(bh8, ul);
            }
            #pragma unroll
            for (int ntl = 0; ntl < 3; ++ntl) {
                int nt = w * 3 + ntl;
                #pragma unroll
                for (int k4 = 0; k4 < 4; ++k4) {
                    int ks = half * 4 + k4;
                    size_t fo = ((size_t)(nt * 8 + ks) * 64 + l) * 8;
                    bh8 bh = *(const bh8*)(catPh + fo);
                    bh8 bm = *(const bh8*)(catPm + fo);
                    bh8 bl = *(const bh8*)(catPl + fo);
                    acc[ntl] = __builtin_amdgcn_mfma_f32_16x16x32_bf16(Ah[k4], bh, acc[ntl], 0, 0, 0);
                    acc[ntl] = __builtin_amdgcn_mfma_f32_16x16x32_bf16(Ah[k4], bm, acc[ntl], 0, 0, 0);
                    acc[ntl] = __builtin_amdgcn_mfma_f32_16x16x32_bf16(Am[k4], bh, acc[ntl], 0, 0, 0);
                    acc[ntl] = __builtin_amdgcn_mfma_f32_16x16x32_bf16(Ah[k4], bl, acc[ntl], 0, 0, 0);
                    acc[ntl] = __builtin_amdgcn_mfma_f32_16x16x32_bf16(Al[k4], bh, acc[ntl], 0, 0, 0);
                    acc[ntl] = __builtin_amdgcn_mfma_f32_16x16x32_bf16(Am[k4], bm, acc[ntl], 0, 0, 0);
                }
            }
        }
        {
            int r0 = (l >> 4) * 4, cbase = w * 48 + (l & 15);
            #pragma unroll
            for (int ntl = 0; ntl < 3; ++ntl)
                #pragma unroll
                for (int reg = 0; reg < 4; ++reg)
                    sOut[(r0 + reg) * 193 + cbase + ntl * 16] = acc[ntl][reg];
        }
        __syncthreads();

        // meta epilogue: 16 rows x 16 units = 256 threads
        {
            int row = t >> 4, u = t & 15, br = u >> 3, nr = u & 7;
            const float* so = sOut + row * 193;
            int c0 = br * 32 + nr * 4;
            float x1 = sig63(so[c0 + 0] + b_idx[c0 + 0]);
            float y1 = sig63(so[c0 + 1] + b_idx[c0 + 1]);
            float x2 = sig63(so[c0 + 2] + b_idx[c0 + 2]);
            float y2 = sig63(so[c0 + 3] + b_idx[c0 + 3]);
            int X1 = (int)ceilf(x1); X1 = X1 < 1 ? 1 : (X1 > 63 ? 63 : X1);
            int X2 = (int)ceilf(x2); X2 = X2 < 1 ? 1 : (X2 > 63 ? 63 : X2);
            int Y1 = (int)ceilf(y1); Y1 = Y1 < 1 ? 1 : (Y1 > 63 ? 63 : Y1);
            int Y2 = (int)ceilf(y2); Y2 = Y2 < 1 ? 1 : (Y2 > 63 ? 63 : Y2);
            float dxa = (float)X1 - x1, dxb = (float)X2 - x2;
            float dya = (float)Y1 - y1, dyb = (float)Y2 - y2;
            int   Xc[4] = {X2, X1, X2, X1};
            int   Yc[4] = {Y2, Y2, Y1, Y1};
            float sg[4] = {1.f, -1.f, -1.f, 1.f};
            float dxc[4] = {dxb, dxa, dxb, dxa};
            float dyc[4] = {dyb, dyb, dya, dya};
            uint* mr = meta + (((rowbase + row) * 16) + (size_t)u) * 32;
            #pragma unroll
            for (int c = 0; c < 4; ++c) {
                uint pt = (uint)(Xc[c] * 64 + Yc[c]);
                float s = sg[c], dx = dxc[c], dy = dyc[c];
                float dx2 = dx * dx, dy2 = dy * dy;
                uint4 wa, wb;
                wa.x = pt * 1024u;
                wa.y = pt * 128u;
                wa.z = pkh(s, s * dy);
                wa.w = pkh(s * dy2, s * dx);
                wb.x = pkh(s * dx2, s * dx * dy);
                wb.y = pkh(s * dx * dy2, s * dx2 * dy);
                wb.z = __builtin_bit_cast(uint, s * dx2 * dy2);
                wb.w = 0u;
                *(uint4*)(mr + c * 8 + 0) = wa;
                *(uint4*)(mr + c * 8 + 4) = wb;
            }
        }
        // softmax epilogue: 16 rows x (2 br x 8 g) = 256 threads
        {
            int row = t >> 4, br = (t >> 3) & 1, g = t & 7;
            const float* so = sOut + row * 193 + 64;
            float lg[8];
            float mx = -1e30f;
            #pragma unroll
            for (int nr = 0; nr < 8; ++nr) {
                int idx = br * 64 + nr * 8 + g;
                lg[nr] = so[idx] + b_mask[idx];
                mx = fmaxf(mx, lg[nr]);
            }
            float s = 0.f;
            #pragma unroll
            for (int nr = 0; nr < 8; ++nr) { lg[nr] = __expf(lg[nr] - mx); s += lg[nr]; }
            float inv = __builtin_amdgcn_rcpf(s);
            #pragma unroll
            for (int nr = 0; nr < 8; ++nr)
                maskw[(rowbase + row) * 128 + br * 64 + nr * 8 + g] = lg[nr] * inv;
        }
    } else {
        // ---------------- k1: LDS-free streaming stencil ----------------
        // bid -> (b, h, cg): cg = bid&3 (16 channels), h = (bid>>2)&63, b = bid>>8
        int cg = bid & 3, h = (bid >> 2) & 63, b = bid >> 8;
        int hp = h > 0 ? h - 1 : 0;
        int c = cg * 16 + (t >> 4);
        int lane16 = t & 15;
        int w0 = lane16 * 4;
        size_t rowb  = (size_t)b * 262144 + (size_t)c * 4096 + (size_t)h  * 64 + w0;
        size_t rowbp = (size_t)b * 262144 + (size_t)c * 4096 + (size_t)hp * 64 + w0;

        float4 Ih  = *(const float4*)(I  + rowb);
        float4 Ihp = *(const float4*)(I  + rowbp);
        float4 Xh  = *(const float4*)(IX + rowb);
        float4 Yh  = *(const float4*)(IY + rowb);
        float4 Yhp = *(const float4*)(IY + rowbp);
        float4 Th  = *(const float4*)(IT + rowb);

        // w-1 boundary values from neighbor lane (clamp at w==0)
        float pI  = __shfl_up(Ih.w,  1, 16);
        float pIp = __shfl_up(Ihp.w, 1, 16);
        float pX  = __shfl_up(Xh.w,  1, 16);
        if (lane16 == 0) { pI = Ih.x; pIp = Ihp.x; pX = Xh.x; }

        float Iv[4]  = {Ih.x, Ih.y, Ih.z, Ih.w};
        float Ipv[4] = {Ihp.x, Ihp.y, Ihp.z, Ihp.w};
        float Xv[4]  = {Xh.x, Xh.y, Xh.z, Xh.w};
        float Yv[4]  = {Yh.x, Yh.y, Yh.z, Yh.w};
        float Ypv[4] = {Yhp.x, Yhp.y, Yhp.z, Yhp.w};
        float Tv[4]  = {Th.x, Th.y, Th.z, Th.w};

        size_t ptb = (((size_t)b * 4096) + (size_t)h * 64 + w0) * 64 + c;
        #pragma unroll
        for (int j = 0; j < 4; ++j) {
            float I00 = Iv[j];
            float I0m = (j == 0) ? pI  : Iv[j - 1];
            float Im0 = Ipv[j];
            float Imm = (j == 0) ? pIp : Ipv[j - 1];
            float Xm  = (j == 0) ? pX  : Xv[j - 1];
            float E1  = Xv[j] - 0.5f * I00;
            float E1m = Xm    - 0.5f * I0m;
            float E2  = Yv[j]  - 0.5f * I00;
            float E2m = Ypv[j] - 0.5f * Im0;
            float v0 = Tv[j];
            float v1 = -E1;
            float v2 = 0.5f * (E1 - E1m);
            float v3 = -E2;
            float v4 = 0.5f * (E2 - E2m);
            float v5 = I00;
            float v6 = 0.5f * (I0m - I00);
            float v7 = 0.5f * (Im0 - I00);
            float v8 = 0.25f * ((Imm - I0m) - (Im0 - I00));
            uint4 o4;
            o4.x = pkh(v0, v1);
            o4.y = pkh(v2, v3);
            o4.z = pkh(v4, v5);
            o4.w = pkh(v6, v7);
            T1[ptb + (size_t)j * 64] = o4;
            T2[ptb + (size_t)j * 64] = (ushort)(pkh(v8, 0.f) & 0xffffu);
        }
    }
}

// ---------------------------------------------------------------------------
// k2: fused sampling + rects GEMM + gelu + mask-sum + LN1.  (round-5 proven
// structure: one d-tile/block, depth-2 gather pipeline, SGPR offsets)
// ---------------------------------------------------------------------------
__global__ __launch_bounds__(256) void k2_rects(
    const uint4* __restrict__ T1, const ushort* __restrict__ T2,
    const uint* __restrict__ meta,
    const ushort* __restrict__ w_projP, const float* __restrict__ b_proj,
    const float* __restrict__ maskw, const float* __restrict__ g1,
    const float* __restrict__ beta1, float* __restrict__ mid)
{
    __shared__ __align__(16) uint meta_lds[16][32];
    __shared__ __align__(16) float S_lds[16][68];
    __shared__ float mrow[128];
    __shared__ float outr[2][128];
    int bid = blockIdx.x;
    int b = bid & 7, d = bid >> 3;
    int t = threadIdx.x, w = t >> 6, l = t & 63;
    size_t tile = (size_t)b * DD + d;
    if (t < 128) {
        uint4 mv = *(const uint4*)(meta + tile * 512 + (size_t)t * 4);
        *(uint4*)(&meta_lds[0][0] + t * 4) = mv;
    }
    if (t >= 128) mrow[t - 128] = maskw[tile * 128 + (t - 128)];

    bh8 bf[2][2];
    #pragma unroll
    for (int ni = 0; ni < 2; ++ni) {
        int nt = w * 2 + ni;
        #pragma unroll
        for (int ks = 0; ks < 2; ++ks)
            bf[ni][ks] = *(const bh8*)(w_projP + ((size_t)(nt * 2 + ks) * 64 + l) * 8);
    }
    __syncthreads();
    const char* t1b = ((const char*)T1) + ((size_t)b << 22) + (size_t)(l * 16);
    const char* t2b = ((const char*)T2) + ((size_t)b << 19) + (size_t)(l * 2);

    int m0 = w * 4;
    uint4 q[2][4]; ushort e8[2][4];
    #pragma unroll
    for (int g = 0; g < 2; ++g) {
        #pragma unroll
        for (int c = 0; c < 4; ++c) {
            uint o1 = __builtin_amdgcn_readfirstlane(meta_lds[m0 + g][c * 8 + 0]);
            uint o2 = __builtin_amdgcn_readfirstlane(meta_lds[m0 + g][c * 8 + 1]);
            q[g][c]  = *(const uint4*)(t1b + o1);
            e8[g][c] = *(const ushort*)(t2b + o2);
        }
    }
    #pragma unroll
    for (int rr = 0; rr < 4; ++rr) {
        int m = m0 + rr;
        int cur = rr & 1;
        uint4 qc[4]; ushort ec[4];
        #pragma unroll
        for (int c = 0; c < 4; ++c) { qc[c] = q[cur][c]; ec[c] = e8[cur][c]; }
        if (rr < 2) {
            int mn = m + 2;
            #pragma unroll
            for (int c = 0; c < 4; ++c) {
                uint o1 = __builtin_amdgcn_readfirstlane(meta_lds[mn][c * 8 + 0]);
                uint o2 = __builtin_amdgcn_readfirstlane(meta_lds[mn][c * 8 + 1]);
                q[cur][c]  = *(const uint4*)(t1b + o1);
                e8[cur][c] = *(const ushort*)(t2b + o2);
            }
        }
        float acc0 = 0.f, acc1 = 0.f;
        #pragma unroll
        for (int c = 0; c < 4; ++c) {
            uint cz = meta_lds[m][c * 8 + 2], cw = meta_lds[m][c * 8 + 3];
            uint bx = meta_lds[m][c * 8 + 4], by = meta_lds[m][c * 8 + 5];
            float bz = asf(meta_lds[m][c * 8 + 6]);
            float ev = __half2float(__builtin_bit_cast(__half, ec[c]));
            float cv = bz * ev;
            cv = fdot2h(ash2f(by), ash2f(qc[c].w), cv);
            cv = fdot2h(ash2f(bx), ash2f(qc[c].z), cv);
            cv = fdot2h(ash2f(cw), ash2f(qc[c].y), cv);
            cv = fdot2h(ash2f(cz), ash2f(qc[c].x), cv);
            if (c & 1) acc1 += cv; else acc0 += cv;
        }
        S_lds[m][l] = acc0 + acc1;
    }
    __syncthreads();

    int am = l & 15, q2 = l >> 4;
    bh8 a0, a1;
    {
        float4 va = *(const float4*)&S_lds[am][q2 * 8];
        float4 vb = *(const float4*)&S_lds[am][q2 * 8 + 4];
        uint4 ua;
        ua.x = cvtpk_bf16(va.x, va.y);
        ua.y = cvtpk_bf16(va.z, va.w);
        ua.z = cvtpk_bf16(vb.x, vb.y);
        ua.w = cvtpk_bf16(vb.z, vb.w);
        a0 = __builtin_bit_cast(bh8, ua);
        float4 vc = *(const float4*)&S_lds[am][32 + q2 * 8];
        float4 vd = *(const float4*)&S_lds[am][32 + q2 * 8 + 4];
        uint4 ub;
        ub.x = cvtpk_bf16(vc.x, vc.y);
        ub.y = cvtpk_bf16(vc.z, vc.w);
        ub.z = cvtpk_bf16(vd.x, vd.y);
        ub.w = cvtpk_bf16(vd.z, vd.w);
        a1 = __builtin_bit_cast(bh8, ub);
    }
    f32x4 cc[2];
    cc[0] = (f32x4){0.f, 0.f, 0.f, 0.f};
    cc[1] = (f32x4){0.f, 0.f, 0.f, 0.f};
    cc[0] = __builtin_amdgcn_mfma_f32_16x16x32_bf16(a0, bf[0][0], cc[0], 0, 0, 0);
    cc[0] = __builtin_amdgcn_mfma_f32_16x16x32_bf16(a1, bf[0][1], cc[0], 0, 0, 0);
    cc[1] = __builtin_amdgcn_mfma_f32_16x16x32_bf16(a0, bf[1][0], cc[1], 0, 0, 0);
    cc[1] = __builtin_amdgcn_mfma_f32_16x16x32_bf16(a1, bf[1][1], cc[1], 0, 0, 0);

    int cl = l & 15;
    #pragma unroll
    for (int ni = 0; ni < 2; ++ni) {
        int nt = w * 2 + ni;
        int col = nt * 16 + cl;
        float bpv = b_proj[col];
        float p = 0.f;
        #pragma unroll
        for (int reg = 0; reg < 4; ++reg) {
            int r = q2 * 4 + reg;
            float v = cc[ni][reg] + bpv;
            p += gelu_fast(v) * mrow[(r >> 3) * 64 + (r & 7) * 8 + nt];
        }
        p += __shfl_xor(p, 16, 64);
        if (q2 == 0) outr[0][col] = p;
        else if (q2 == 2) outr[1][col] = p;
    }
    __syncthreads();

    if (w < 2) {
        float v0 = outr[w][l], v1 = outr[w][l + 64];
        float s = v0 + v1, sq = v0 * v0 + v1 * v1;
        #pragma unroll
        for (int mm = 32; mm > 0; mm >>= 1) {
            s  += __shfl_xor(s, mm, 64);
            sq += __shfl_xor(sq, mm, 64);
        }
        float mu  = s * (1.0f / 128.0f);
        float var = sq * (1.0f / 128.0f) - mu * mu;
        float rs  = rsqrtf(var + 1e-5f);
        size_t ob = (tile * 2 + w) * 128;
        mid[ob + l]      = (v0 - mu) * rs * g1[l]      + beta1[l];
        mid[ob + l + 64] = (v1 - mu) * rs * g1[l + 64] + beta1[l + 64];
    }
}

// ---------------------------------------------------------------------------
// k4: MLP 128->512(gelu)->128 via MFMA, 16 rows/block, + LN2 + residual.
// ---------------------------------------------------------------------------
__global__ __launch_bounds__(256) void k4_mlp(
    const float* __restrict__ mid, const ushort* __restrict__ w1P,
    const float* __restrict__ b1, const ushort* __restrict__ w2P,
    const float* __restrict__ b2, const float* __restrict__ g2,
    const float* __restrict__ beta2, float* __restrict__ outp)
{
    __shared__ float xr[16][132];
    __shared__ __align__(16) ushort Af[4][64][8];
    __shared__ __align__(16) ushort H[16][520];
    __shared__ float oo[16][128];
    __shared__ float b1s[512];
    __shared__ float b2s[128], g2s[128], bt2s[128];
    int t = threadIdx.x, w = t >> 6, l = t & 63;
    int bid = blockIdx.x;
    int mt = (bid & 7) * 128 + (bid >> 3);   // XCD-local by batch
    size_t rowbase = (size_t)mt * 16;

    {
        const float4* mg = (const float4*)(mid + rowbase * 128);
        #pragma unroll
        for (int i4 = 0; i4 < 2; ++i4) {
            int i = i4 * 256 + t;
            float4 v = mg[i];
            *(float4*)(&xr[i >> 5][(i & 31) * 4]) = v;
        }
    }
    for (int i = t; i < 512; i += 256) b1s[i] = b1[i];
    if (t < 128) { b2s[t] = b2[t]; g2s[t] = g2[t]; bt2s[t] = beta2[t]; }
    __syncthreads();

    {
        int ks = t >> 6, m = l & 15, c0 = ks * 32 + (l >> 4) * 8;
        uint* dst = (uint*)&Af[ks][l][0];
        #pragma unroll
        for (int j = 0; j < 4; ++j)
            dst[j] = cvtpk_bf16(xr[m][c0 + 2 * j], xr[m][c0 + 2 * j + 1]);
    }
    __syncthreads();

    f32x4 c1[8];
    #pragma unroll
    for (int i = 0; i < 8; ++i) c1[i] = (f32x4){0.f, 0.f, 0.f, 0.f};
    bh8 a[4];
    #pragma unroll
    for (int ks = 0; ks < 4; ++ks) a[ks] = *(const bh8*)&Af[ks][l][0];
    #pragma unroll
    for (int ni = 0; ni < 8; ++ni) {
        int nt = w * 8 + ni;
        #pragma unroll
        for (int ks = 0; ks < 4; ++ks) {
            bh8 bfr = *(const bh8*)(w1P + ((size_t)(nt * 4 + ks) * 64 + l) * 8);
            c1[ni] = __builtin_amdgcn_mfma_f32_16x16x32_bf16(a[ks], bfr, c1[ni], 0, 0, 0);
        }
    }
    #pragma unroll
    for (int ni = 0; ni < 8; ++ni) {
        int nt = w * 8 + ni;
        int col = nt * 16 + (l & 15);
        int r0 = (l >> 4) * 4;
        #pragma unroll
        for (int reg = 0; reg < 4; ++reg)
            H[r0 + reg][col] = cvt1_bf16(gelu_fast(c1[ni][reg] + b1s[col]));
    }
    __syncthreads();

    f32x4 c2[2];
    c2[0] = (f32x4){0.f, 0.f, 0.f, 0.f};
    c2[1] = (f32x4){0.f, 0.f, 0.f, 0.f};
    const char* hb = (const char*)&H[0][0];
    #pragma unroll
    for (int ks2 = 0; ks2 < 16; ++ks2) {
        bh8 af = *(const bh8*)(hb + (l & 15) * 1040 + ks2 * 64 + (l >> 4) * 16);
        #pragma unroll
        for (int i = 0; i < 2; ++i) {
            int nt2 = w * 2 + i;
            bh8 bfr = *(const bh8*)(w2P + ((size_t)(nt2 * 16 + ks2) * 64 + l) * 8);
            c2[i] = __builtin_amdgcn_mfma_f32_16x16x32_bf16(af, bfr, c2[i], 0, 0, 0);
        }
    }
    #pragma unroll
    for (int i = 0; i < 2; ++i) {
        int col = (w * 2 + i) * 16 + (l & 15);
        int r0 = (l >> 4) * 4;
        #pragma unroll
        for (int reg = 0; reg < 4; ++reg) oo[r0 + reg][col] = c2[i][reg] + b2s[col];
    }
    __syncthreads();

    #pragma unroll
    for (int rr = 0; rr < 4; ++rr) {
        int r = w * 4 + rr;
        float v0 = oo[r][l], v1 = oo[r][l + 64];
        float s = v0 + v1, sq = v0 * v0 + v1 * v1;
        #pragma unroll
        for (int m = 32; m > 0; m >>= 1) {
            s  += __shfl_xor(s, m, 64);
            sq += __shfl_xor(sq, m, 64);
        }
        float mu  = s * (1.0f / 128.0f);
        float var = sq * (1.0f / 128.0f) - mu * mu;
        float rs  = rsqrtf(var + 1e-5f);
        size_t ob = (rowbase + r) * 128;
        outp[ob + l]      = (v0 - mu) * rs * g2s[l]      + bt2s[l]      + xr[r][l];
        outp[ob + l + 64] = (v1 - mu) * rs * g2s[l + 64] + bt2s[l + 64] + xr[r][l + 64];
    }
}

// ---------------------------------------------------------------------------
extern "C" void kernel_launch(void* const* d_in, const int* in_sizes, int n_in,
                              void* d_out, int out_size, void* d_ws, size_t ws_size,
                              hipStream_t stream) {
    const float* x      = (const float*)d_in[0];
    const float* I      = (const float*)d_in[1];
    const float* IX     = (const float*)d_in[2];
    const float* IY     = (const float*)d_in[3];
    const float* IT     = (const float*)d_in[4];
    const float* w_idx  = (const float*)d_in[5];
    const float* b_idx  = (const float*)d_in[6];
    const float* w_proj = (const float*)d_in[7];
    const float* b_proj = (const float*)d_in[8];
    const float* w_mask = (const float*)d_in[9];
    const float* b_mask = (const float*)d_in[10];
    const float* g1     = (const float*)d_in[11];
    const float* beta1  = (const float*)d_in[12];
    const float* w_mlp1 = (const float*)d_in[13];
    const float* b_mlp1 = (const float*)d_in[14];
    const float* w_mlp2 = (const float*)d_in[15];
    const float* b_mlp2 = (const float*)d_in[16];
    const float* g2     = (const float*)d_in[17];
    const float* beta2  = (const float*)d_in[18];
    float* out = (float*)d_out;

    float* ws = (float*)d_ws;
    ushort* catPh  = (ushort*)ws;                  // 49152 us -> 24576 f
    ushort* catPm  = (ushort*)(ws + 24576);        // 49152 us -> 49152 f
    ushort* catPl  = (ushort*)(ws + 49152);        // 49152 us -> 73728 f
    ushort* w_projP = (ushort*)(ws + 73728);       // 8192 us  -> 77824
    ushort* w1P     = (ushort*)(ws + 77824);       // 65536 us -> 110592
    ushort* w2P     = (ushort*)(ws + 110592);      // 65536 us -> 143360
    float*  maskw   = ws + 143360;                 // 1048576 f -> 1191936
    uint*   meta    = (uint*)(ws + 1191936);       // 4194304 w -> 5386240
    uint4*  T1      = (uint4*)(ws + 5386240);      // 2097152 u4 -> 13774848
    ushort* T2      = (ushort*)(ws + 13774848);    // 2097152 us -> 14823424 (59MB)

    kT_pack<<<92, 256, 0, stream>>>(w_idx, w_mask, w_proj, w_mlp1, w_mlp2,
                                    catPh, catPm, catPl, w_projP, w1P, w2P);
    k01<<<2560, 256, 0, stream>>>(x, catPh, catPm, catPl, b_idx, b_mask,
                                  maskw, meta, I, IX, IY, IT, T1, T2);
    k2_rects<<<8192, 256, 0, stream>>>(T1, T2, meta, w_projP, b_proj, maskw,
                                       g1, beta1, out);
    k4_mlp<<<1024, 256, 0, stream>>>(out, w1P, b_mlp1, w2P, b_mlp2, g2, beta2, out);
}

// Round 9
// 86.648 us; speedup vs baseline: 1.0961x; 1.0828x over previous
//
#include <hip/hip_runtime.h>
#include <hip/hip_bf16.h>
#include <hip/hip_fp16.h>
#include <math.h>

#define BB   8
#define DD   1024

typedef short bh8 __attribute__((ext_vector_type(8)));
typedef float f32x4 __attribute__((ext_vector_type(4)));
typedef _Float16 h2f __attribute__((ext_vector_type(2)));

__device__ __forceinline__ ushort f2bf(float f) {
    uint u = __builtin_bit_cast(uint, f);
    u += 0x7fffu + ((u >> 16) & 1u);
    return (ushort)(u >> 16);
}
__device__ __forceinline__ float asf(uint u)  { return __builtin_bit_cast(float, u); }
__device__ __forceinline__ float bflo(uint u) { return __builtin_bit_cast(float, u << 16); }
__device__ __forceinline__ float bfhi(uint u) { return __builtin_bit_cast(float, u & 0xffff0000u); }
__device__ __forceinline__ uint  pkh(float a, float b) {
    return __builtin_bit_cast(uint, __builtin_amdgcn_cvt_pkrtz(a, b));
}
__device__ __forceinline__ h2f ash2f(uint u) { return __builtin_bit_cast(h2f, u); }

#if __has_builtin(__builtin_amdgcn_fdot2)
__device__ __forceinline__ float fdot2h(h2f a, h2f b, float c) {
    return __builtin_amdgcn_fdot2(a, b, c, false);
}
#else
__device__ __forceinline__ float fdot2h(h2f a, h2f b, float c) {
    return fmaf((float)a.x, (float)b.x, fmaf((float)a.y, (float)b.y, c));
}
#endif

// hardware packed f32->bf16 RTNE (no builtin on gfx950; asm per guide recipe)
__device__ __forceinline__ uint cvtpk_bf16(float a, float b) {
    uint r;
    asm("v_cvt_pk_bf16_f32 %0, %1, %2" : "=v"(r) : "v"(a), "v"(b));
    return r;
}
__device__ __forceinline__ ushort cvt1_bf16(float a) {
    uint r;
    asm("v_cvt_pk_bf16_f32 %0, %1, %2" : "=v"(r) : "v"(a), "v"(a));
    return (ushort)r;
}

// overflow-safe tanh-form gelu via exp2 + rcp
__device__ __forceinline__ float gelu_fast(float x) {
    float x2 = x * x;
#if __has_builtin(__builtin_amdgcn_exp2f)
    float e = __builtin_amdgcn_exp2f(x * fmaf(x2, -0.20588652f, -2.3022082f));
#else
    float e = __expf(-(1.5957691216f * x + 0.14270963f * x * x2));
#endif
    return x * __builtin_amdgcn_rcpf(1.0f + e);
}
__device__ __forceinline__ float sig63(float v) {
    return 63.0f * __builtin_amdgcn_rcpf(1.0f + __expf(-v));
}

// ---------------------------------------------------------------------------
// kT: ALL weight preprocessing (3-way split w_cat + proj/mlp fragment packs).
// ---------------------------------------------------------------------------
__global__ __launch_bounds__(256) void kT_pack(
    const float* __restrict__ w_idx, const float* __restrict__ w_mask,
    const float* __restrict__ w_proj, const float* __restrict__ w1,
    const float* __restrict__ w2,
    ushort* __restrict__ catPh, ushort* __restrict__ catPm,
    ushort* __restrict__ catPl,
    ushort* __restrict__ w_projP, ushort* __restrict__ w1P,
    ushort* __restrict__ w2P)
{
    int bid = blockIdx.x, t = threadIdx.x;
    if (bid < 24) {
        int gid = bid * 256 + t;                  // [0,6144)
        int l = gid & 63, ks = (gid >> 6) & 7, nt = gid >> 9;
        int n = nt * 16 + (l & 15);
        int kbase = ks * 32 + ((l >> 4) << 3);
        const float* src = (n < 64) ? (w_idx + (size_t)n * 256)
                                    : (w_mask + (size_t)(n - 64) * 256);
        ushort* dh = catPh + (size_t)gid * 8;
        ushort* dm = catPm + (size_t)gid * 8;
        ushort* dl = catPl + (size_t)gid * 8;
        #pragma unroll
        for (int j = 0; j < 8; ++j) {
            float v = src[kbase + j];
            ushort h = f2bf(v);
            float hf = __builtin_bit_cast(float, (uint)h << 16);
            float r1 = v - hf;
            ushort m = f2bf(r1); float mf = __builtin_bit_cast(float, (uint)m << 16);
            ushort lo = f2bf(r1 - mf);
            dh[j] = h; dm[j] = m; dl[j] = lo;
        }
    } else if (bid < 28) {               // w_proj (128,64): B[k=c][n=dch]
        int g = (bid - 24) * 256 + t;    // [0,1024)
        int nt = g >> 7, ks = (g >> 6) & 1, l = g & 63;
        int n = nt * 16 + (l & 15), k0 = ks * 32 + (l >> 4) * 8;
        ushort* dst = w_projP + (size_t)g * 8;
        #pragma unroll
        for (int j = 0; j < 8; ++j) dst[j] = f2bf(w_proj[n * 64 + k0 + j]);
    } else if (bid < 60) {               // w_mlp1 (512,128): B[k][n]
        int g = (bid - 28) * 256 + t;    // [0,8192)
        int nt = g >> 8, ks = (g >> 6) & 3, l = g & 63;
        int n = nt * 16 + (l & 15), k0 = ks * 32 + (l >> 4) * 8;
        ushort* dst = w1P + (size_t)g * 8;
        #pragma unroll
        for (int j = 0; j < 8; ++j) dst[j] = f2bf(w1[n * 128 + k0 + j]);
    } else {                             // w_mlp2 (128,512): B[k][n]
        int g = (bid - 60) * 256 + t;    // [0,8192)
        int nt = g >> 10, ks = (g >> 6) & 15, l = g & 63;
        int n = nt * 16 + (l & 15), k0 = ks * 32 + (l >> 4) * 8;
        ushort* dst = w2P + (size_t)g * 8;
        #pragma unroll
        for (int j = 0; j < 8; ++j) dst[j] = f2bf(w2[n * 512 + k0 + j]);
    }
}

// ---------------------------------------------------------------------------
// k01: fat kernel (round-5 proven config, restored).
//  blocks [0,512)    : k0 via MFMA (3-way bf16 split) + meta/softmax epilogue
//  blocks [512,2560) : k1 texture coefficients, 16 channels/block, float4
//                      staging. kb = h*32 + col (col = b*4+chunk) so every
//                      (b,chunk) column pins to one XCD -> h-1 rows L2-warm.
// ---------------------------------------------------------------------------
__global__ __launch_bounds__(256) void k01(
    const float* __restrict__ x,
    const ushort* __restrict__ catPh, const ushort* __restrict__ catPm,
    const ushort* __restrict__ catPl,
    const float* __restrict__ b_idx, const float* __restrict__ b_mask,
    float* __restrict__ maskw, uint* __restrict__ meta,
    const float* __restrict__ I, const float* __restrict__ IX,
    const float* __restrict__ IY, const float* __restrict__ IT,
    uint4* __restrict__ T1, ushort* __restrict__ T2)
{
    __shared__ __align__(16) float sf[6528];      // 26112 B
    int t = threadIdx.x;
    int bid = blockIdx.x;

    if (bid < 512) {
        // ---------------- k0: coords + mask via MFMA ----------------
        float* sOut = sf;                          // [16][193] = 3088 f
        size_t rowbase = (size_t)bid * 16;
        int w = t >> 6, l = t & 63;

        f32x4 acc[3];
        acc[0] = (f32x4){0.f,0.f,0.f,0.f};
        acc[1] = (f32x4){0.f,0.f,0.f,0.f};
        acc[2] = (f32x4){0.f,0.f,0.f,0.f};
        const float* xr = x + (rowbase + (size_t)(l & 15)) * 256 + ((l >> 4) << 3);

        #pragma unroll
        for (int half = 0; half < 2; ++half) {
            bh8 Ah[4], Am[4], Al[4];
            #pragma unroll
            for (int k4 = 0; k4 < 4; ++k4) {
                int ks = half * 4 + k4;
                float4 v0 = *(const float4*)(xr + ks * 32);
                float4 v1 = *(const float4*)(xr + ks * 32 + 4);
                uint4 uh, um, ul;
                uh.x = cvtpk_bf16(v0.x, v0.y);
                uh.y = cvtpk_bf16(v0.z, v0.w);
                uh.z = cvtpk_bf16(v1.x, v1.y);
                uh.w = cvtpk_bf16(v1.z, v1.w);
                float r0a = v0.x - bflo(uh.x), r0b = v0.y - bfhi(uh.x);
                float r0c = v0.z - bflo(uh.y), r0d = v0.w - bfhi(uh.y);
                float r1a = v1.x - bflo(uh.z), r1b = v1.y - bfhi(uh.z);
                float r1c = v1.z - bflo(uh.w), r1d = v1.w - bfhi(uh.w);
                um.x = cvtpk_bf16(r0a, r0b);
                um.y = cvtpk_bf16(r0c, r0d);
                um.z = cvtpk_bf16(r1a, r1b);
                um.w = cvtpk_bf16(r1c, r1d);
                ul.x = cvtpk_bf16(r0a - bflo(um.x), r0b - bfhi(um.x));
                ul.y = cvtpk_bf16(r0c - bflo(um.y), r0d - bfhi(um.y));
                ul.z = cvtpk_bf16(r1a - bflo(um.z), r1b - bfhi(um.z));
                ul.w = cvtpk_bf16(r1c - bflo(um.w), r1d - bfhi(um.w));
                Ah[k4] = __builtin_bit_cast(bh8, uh);
                Am[k4] = __builtin_bit_cast(bh8, um);
                Al[k4] = __builtin_bit_cast(bh8, ul);
            }
            #pragma unroll
            for (int ntl = 0; ntl < 3; ++ntl) {
                int nt = w * 3 + ntl;
                #pragma unroll
                for (int k4 = 0; k4 < 4; ++k4) {
                    int ks = half * 4 + k4;
                    size_t fo = ((size_t)(nt * 8 + ks) * 64 + l) * 8;
                    bh8 bh = *(const bh8*)(catPh + fo);
                    bh8 bm = *(const bh8*)(catPm + fo);
                    bh8 bl = *(const bh8*)(catPl + fo);
                    acc[ntl] = __builtin_amdgcn_mfma_f32_16x16x32_bf16(Ah[k4], bh, acc[ntl], 0, 0, 0);
                    acc[ntl] = __builtin_amdgcn_mfma_f32_16x16x32_bf16(Ah[k4], bm, acc[ntl], 0, 0, 0);
                    acc[ntl] = __builtin_amdgcn_mfma_f32_16x16x32_bf16(Am[k4], bh, acc[ntl], 0, 0, 0);
                    acc[ntl] = __builtin_amdgcn_mfma_f32_16x16x32_bf16(Ah[k4], bl, acc[ntl], 0, 0, 0);
                    acc[ntl] = __builtin_amdgcn_mfma_f32_16x16x32_bf16(Al[k4], bh, acc[ntl], 0, 0, 0);
                    acc[ntl] = __builtin_amdgcn_mfma_f32_16x16x32_bf16(Am[k4], bm, acc[ntl], 0, 0, 0);
                }
            }
        }
        {
            int r0 = (l >> 4) * 4, cbase = w * 48 + (l & 15);
            #pragma unroll
            for (int ntl = 0; ntl < 3; ++ntl)
                #pragma unroll
                for (int reg = 0; reg < 4; ++reg)
                    sOut[(r0 + reg) * 193 + cbase + ntl * 16] = acc[ntl][reg];
        }
        __syncthreads();

        // meta epilogue: 16 rows x 16 units = 256 threads
        {
            int row = t >> 4, u = t & 15, br = u >> 3, nr = u & 7;
            const float* so = sOut + row * 193;
            int c0 = br * 32 + nr * 4;
            float x1 = sig63(so[c0 + 0] + b_idx[c0 + 0]);
            float y1 = sig63(so[c0 + 1] + b_idx[c0 + 1]);
            float x2 = sig63(so[c0 + 2] + b_idx[c0 + 2]);
            float y2 = sig63(so[c0 + 3] + b_idx[c0 + 3]);
            int X1 = (int)ceilf(x1); X1 = X1 < 1 ? 1 : (X1 > 63 ? 63 : X1);
            int X2 = (int)ceilf(x2); X2 = X2 < 1 ? 1 : (X2 > 63 ? 63 : X2);
            int Y1 = (int)ceilf(y1); Y1 = Y1 < 1 ? 1 : (Y1 > 63 ? 63 : Y1);
            int Y2 = (int)ceilf(y2); Y2 = Y2 < 1 ? 1 : (Y2 > 63 ? 63 : Y2);
            float dxa = (float)X1 - x1, dxb = (float)X2 - x2;
            float dya = (float)Y1 - y1, dyb = (float)Y2 - y2;
            int   Xc[4] = {X2, X1, X2, X1};
            int   Yc[4] = {Y2, Y2, Y1, Y1};
            float sg[4] = {1.f, -1.f, -1.f, 1.f};
            float dxc[4] = {dxb, dxa, dxb, dxa};
            float dyc[4] = {dyb, dyb, dya, dya};
            uint* mr = meta + (((rowbase + row) * 16) + (size_t)u) * 32;
            #pragma unroll
            for (int c = 0; c < 4; ++c) {
                uint pt = (uint)(Xc[c] * 64 + Yc[c]);
                float s = sg[c], dx = dxc[c], dy = dyc[c];
                float dx2 = dx * dx, dy2 = dy * dy;
                uint4 wa, wb;
                wa.x = pt * 1024u;
                wa.y = pt * 128u;
                wa.z = pkh(s, s * dy);
                wa.w = pkh(s * dy2, s * dx);
                wb.x = pkh(s * dx2, s * dx * dy);
                wb.y = pkh(s * dx * dy2, s * dx2 * dy);
                wb.z = __builtin_bit_cast(uint, s * dx2 * dy2);
                wb.w = 0u;
                *(uint4*)(mr + c * 8 + 0) = wa;
                *(uint4*)(mr + c * 8 + 4) = wb;
            }
        }
        // softmax epilogue: 16 rows x (2 br x 8 g) = 256 threads
        {
            int row = t >> 4, br = (t >> 3) & 1, g = t & 7;
            const float* so = sOut + row * 193 + 64;
            float lg[8];
            float mx = -1e30f;
            #pragma unroll
            for (int nr = 0; nr < 8; ++nr) {
                int idx = br * 64 + nr * 8 + g;
                lg[nr] = so[idx] + b_mask[idx];
                mx = fmaxf(mx, lg[nr]);
            }
            float s = 0.f;
            #pragma unroll
            for (int nr = 0; nr < 8; ++nr) { lg[nr] = __expf(lg[nr] - mx); s += lg[nr]; }
            float inv = __builtin_amdgcn_rcpf(s);
            #pragma unroll
            for (int nr = 0; nr < 8; ++nr)
                maskw[(rowbase + row) * 128 + br * 64 + nr * 8 + g] = lg[nr] * inv;
        }
    } else {
        // ---------------- k1: 9-coeff texture, 16 channels/block ------------
        // kb = h*32 + col, col = b*4 + chunk  ->  kb%8 const per column (XCD)
        int kb = bid - 512;
        int col = kb & 31, h = kb >> 5;
        int b = col >> 2, chunk = col & 3;
        int hp = h > 0 ? h - 1 : 0;
        int cb = chunk * 16;
        size_t inb  = (size_t)b * 262144 + (size_t)h  * 64;
        size_t inbp = (size_t)b * 262144 + (size_t)hp * 64;

        {
            int c = t >> 4, w4 = (t & 15) << 2;
            size_t o = (size_t)(cb + c) * 4096 + w4;
            int so = c * 68 + w4;
            *(float4*)(sf + 0 * 1088 + so) = *(const float4*)(I  + inb  + o);
            *(float4*)(sf + 1 * 1088 + so) = *(const float4*)(I  + inbp + o);
            *(float4*)(sf + 2 * 1088 + so) = *(const float4*)(IX + inb  + o);
            *(float4*)(sf + 3 * 1088 + so) = *(const float4*)(IY + inb  + o);
            *(float4*)(sf + 4 * 1088 + so) = *(const float4*)(IY + inbp + o);
            *(float4*)(sf + 5 * 1088 + so) = *(const float4*)(IT + inb  + o);
        }
        __syncthreads();

        #pragma unroll
        for (int i = 0; i < 4; ++i) {
            int idx = i * 256 + t; int w = idx >> 4, c = idx & 15;
            int wm = w > 0 ? w - 1 : 0;
            int rb = c * 68;
            float I00 = sf[rb + w],        I0m = sf[rb + wm];
            float Im0 = sf[1088 + rb + w], Imm = sf[1088 + rb + wm];
            float E1  = sf[2176 + rb + w]  - 0.5f * I00;
            float E1m = sf[2176 + rb + wm] - 0.5f * I0m;
            float E2  = sf[3264 + rb + w]  - 0.5f * I00;
            float E2m = sf[4352 + rb + w]  - 0.5f * Im0;
            float v0 = sf[5440 + rb + w];
            float v1 = -E1;
            float v2 = 0.5f * (E1 - E1m);
            float v3 = -E2;
            float v4 = 0.5f * (E2 - E2m);
            float v5 = I00;
            float v6 = 0.5f * (I0m - I00);
            float v7 = 0.5f * (Im0 - I00);
            float v8 = 0.25f * ((Imm - I0m) - (Im0 - I00));
            size_t pt = (((size_t)b * 4096) + (size_t)h * 64 + w) * 64 + (cb + c);
            uint4 o4;
            o4.x = pkh(v0, v1);
            o4.y = pkh(v2, v3);
            o4.z = pkh(v4, v5);
            o4.w = pkh(v6, v7);
            T1[pt] = o4;
            T2[pt] = (ushort)(pkh(v8, 0.f) & 0xffffu);
        }
    }
}

// ---------------------------------------------------------------------------
// k2: fused sampling + rects GEMM + gelu + mask-sum + LN1.  (round-5 proven
// structure: one d-tile/block, depth-2 gather pipeline, SGPR offsets)
// ---------------------------------------------------------------------------
__global__ __launch_bounds__(256) void k2_rects(
    const uint4* __restrict__ T1, const ushort* __restrict__ T2,
    const uint* __restrict__ meta,
    const ushort* __restrict__ w_projP, const float* __restrict__ b_proj,
    const float* __restrict__ maskw, const float* __restrict__ g1,
    const float* __restrict__ beta1, float* __restrict__ mid)
{
    __shared__ __align__(16) uint meta_lds[16][32];
    __shared__ __align__(16) float S_lds[16][68];
    __shared__ float mrow[128];
    __shared__ float outr[2][128];
    int bid = blockIdx.x;
    int b = bid & 7, d = bid >> 3;
    int t = threadIdx.x, w = t >> 6, l = t & 63;
    size_t tile = (size_t)b * DD + d;
    if (t < 128) {
        uint4 mv = *(const uint4*)(meta + tile * 512 + (size_t)t * 4);
        *(uint4*)(&meta_lds[0][0] + t * 4) = mv;
    }
    if (t >= 128) mrow[t - 128] = maskw[tile * 128 + (t - 128)];

    bh8 bf[2][2];
    #pragma unroll
    for (int ni = 0; ni < 2; ++ni) {
        int nt = w * 2 + ni;
        #pragma unroll
        for (int ks = 0; ks < 2; ++ks)
            bf[ni][ks] = *(const bh8*)(w_projP + ((size_t)(nt * 2 + ks) * 64 + l) * 8);
    }
    __syncthreads();
    const char* t1b = ((const char*)T1) + ((size_t)b << 22) + (size_t)(l * 16);
    const char* t2b = ((const char*)T2) + ((size_t)b << 19) + (size_t)(l * 2);

    int m0 = w * 4;
    uint4 q[2][4]; ushort e8[2][4];
    #pragma unroll
    for (int g = 0; g < 2; ++g) {
        #pragma unroll
        for (int c = 0; c < 4; ++c) {
            uint o1 = __builtin_amdgcn_readfirstlane(meta_lds[m0 + g][c * 8 + 0]);
            uint o2 = __builtin_amdgcn_readfirstlane(meta_lds[m0 + g][c * 8 + 1]);
            q[g][c]  = *(const uint4*)(t1b + o1);
            e8[g][c] = *(const ushort*)(t2b + o2);
        }
    }
    #pragma unroll
    for (int rr = 0; rr < 4; ++rr) {
        int m = m0 + rr;
        int cur = rr & 1;
        uint4 qc[4]; ushort ec[4];
        #pragma unroll
        for (int c = 0; c < 4; ++c) { qc[c] = q[cur][c]; ec[c] = e8[cur][c]; }
        if (rr < 2) {
            int mn = m + 2;
            #pragma unroll
            for (int c = 0; c < 4; ++c) {
                uint o1 = __builtin_amdgcn_readfirstlane(meta_lds[mn][c * 8 + 0]);
                uint o2 = __builtin_amdgcn_readfirstlane(meta_lds[mn][c * 8 + 1]);
                q[cur][c]  = *(const uint4*)(t1b + o1);
                e8[cur][c] = *(const ushort*)(t2b + o2);
            }
        }
        float acc0 = 0.f, acc1 = 0.f;
        #pragma unroll
        for (int c = 0; c < 4; ++c) {
            uint cz = meta_lds[m][c * 8 + 2], cw = meta_lds[m][c * 8 + 3];
            uint bx = meta_lds[m][c * 8 + 4], by = meta_lds[m][c * 8 + 5];
            float bz = asf(meta_lds[m][c * 8 + 6]);
            float ev = __half2float(__builtin_bit_cast(__half, ec[c]));
            float cv = bz * ev;
            cv = fdot2h(ash2f(by), ash2f(qc[c].w), cv);
            cv = fdot2h(ash2f(bx), ash2f(qc[c].z), cv);
            cv = fdot2h(ash2f(cw), ash2f(qc[c].y), cv);
            cv = fdot2h(ash2f(cz), ash2f(qc[c].x), cv);
            if (c & 1) acc1 += cv; else acc0 += cv;
        }
        S_lds[m][l] = acc0 + acc1;
    }
    __syncthreads();

    int am = l & 15, q2 = l >> 4;
    bh8 a0, a1;
    {
        float4 va = *(const float4*)&S_lds[am][q2 * 8];
        float4 vb = *(const float4*)&S_lds[am][q2 * 8 + 4];
        uint4 ua;
        ua.x = cvtpk_bf16(va.x, va.y);
        ua.y = cvtpk_bf16(va.z, va.w);
        ua.z = cvtpk_bf16(vb.x, vb.y);
        ua.w = cvtpk_bf16(vb.z, vb.w);
        a0 = __builtin_bit_cast(bh8, ua);
        float4 vc = *(const float4*)&S_lds[am][32 + q2 * 8];
        float4 vd = *(const float4*)&S_lds[am][32 + q2 * 8 + 4];
        uint4 ub;
        ub.x = cvtpk_bf16(vc.x, vc.y);
        ub.y = cvtpk_bf16(vc.z, vc.w);
        ub.z = cvtpk_bf16(vd.x, vd.y);
        ub.w = cvtpk_bf16(vd.z, vd.w);
        a1 = __builtin_bit_cast(bh8, ub);
    }
    f32x4 cc[2];
    cc[0] = (f32x4){0.f, 0.f, 0.f, 0.f};
    cc[1] = (f32x4){0.f, 0.f, 0.f, 0.f};
    cc[0] = __builtin_amdgcn_mfma_f32_16x16x32_bf16(a0, bf[0][0], cc[0], 0, 0, 0);
    cc[0] = __builtin_amdgcn_mfma_f32_16x16x32_bf16(a1, bf[0][1], cc[0], 0, 0, 0);
    cc[1] = __builtin_amdgcn_mfma_f32_16x16x32_bf16(a0, bf[1][0], cc[1], 0, 0, 0);
    cc[1] = __builtin_amdgcn_mfma_f32_16x16x32_bf16(a1, bf[1][1], cc[1], 0, 0, 0);

    int cl = l & 15;
    #pragma unroll
    for (int ni = 0; ni < 2; ++ni) {
        int nt = w * 2 + ni;
        int col = nt * 16 + cl;
        float bpv = b_proj[col];
        float p = 0.f;
        #pragma unroll
        for (int reg = 0; reg < 4; ++reg) {
            int r = q2 * 4 + reg;
            float v = cc[ni][reg] + bpv;
            p += gelu_fast(v) * mrow[(r >> 3) * 64 + (r & 7) * 8 + nt];
        }
        p += __shfl_xor(p, 16, 64);
        if (q2 == 0) outr[0][col] = p;
        else if (q2 == 2) outr[1][col] = p;
    }
    __syncthreads();

    if (w < 2) {
        float v0 = outr[w][l], v1 = outr[w][l + 64];
        float s = v0 + v1, sq = v0 * v0 + v1 * v1;
        #pragma unroll
        for (int mm = 32; mm > 0; mm >>= 1) {
            s  += __shfl_xor(s, mm, 64);
            sq += __shfl_xor(sq, mm, 64);
        }
        float mu  = s * (1.0f / 128.0f);
        float var = sq * (1.0f / 128.0f) - mu * mu;
        float rs  = rsqrtf(var + 1e-5f);
        size_t ob = (tile * 2 + w) * 128;
        mid[ob + l]      = (v0 - mu) * rs * g1[l]      + beta1[l];
        mid[ob + l + 64] = (v1 - mu) * rs * g1[l + 64] + beta1[l + 64];
    }
}

// ---------------------------------------------------------------------------
// k4: MLP 128->512(gelu)->128 via MFMA, 16 rows/block, + LN2 + residual.
// ---------------------------------------------------------------------------
__global__ __launch_bounds__(256) void k4_mlp(
    const float* __restrict__ mid, const ushort* __restrict__ w1P,
    const float* __restrict__ b1, const ushort* __restrict__ w2P,
    const float* __restrict__ b2, const float* __restrict__ g2,
    const float* __restrict__ beta2, float* __restrict__ outp)
{
    __shared__ float xr[16][132];
    __shared__ __align__(16) ushort Af[4][64][8];
    __shared__ __align__(16) ushort H[16][520];
    __shared__ float oo[16][128];
    __shared__ float b1s[512];
    __shared__ float b2s[128], g2s[128], bt2s[128];
    int t = threadIdx.x, w = t >> 6, l = t & 63;
    int bid = blockIdx.x;
    int mt = (bid & 7) * 128 + (bid >> 3);   // XCD-local by batch
    size_t rowbase = (size_t)mt * 16;

    {
        const float4* mg = (const float4*)(mid + rowbase * 128);
        #pragma unroll
        for (int i4 = 0; i4 < 2; ++i4) {
            int i = i4 * 256 + t;
            float4 v = mg[i];
            *(float4*)(&xr[i >> 5][(i & 31) * 4]) = v;
        }
    }
    for (int i = t; i < 512; i += 256) b1s[i] = b1[i];
    if (t < 128) { b2s[t] = b2[t]; g2s[t] = g2[t]; bt2s[t] = beta2[t]; }
    __syncthreads();

    {
        int ks = t >> 6, m = l & 15, c0 = ks * 32 + (l >> 4) * 8;
        uint* dst = (uint*)&Af[ks][l][0];
        #pragma unroll
        for (int j = 0; j < 4; ++j)
            dst[j] = cvtpk_bf16(xr[m][c0 + 2 * j], xr[m][c0 + 2 * j + 1]);
    }
    __syncthreads();

    f32x4 c1[8];
    #pragma unroll
    for (int i = 0; i < 8; ++i) c1[i] = (f32x4){0.f, 0.f, 0.f, 0.f};
    bh8 a[4];
    #pragma unroll
    for (int ks = 0; ks < 4; ++ks) a[ks] = *(const bh8*)&Af[ks][l][0];
    #pragma unroll
    for (int ni = 0; ni < 8; ++ni) {
        int nt = w * 8 + ni;
        #pragma unroll
        for (int ks = 0; ks < 4; ++ks) {
            bh8 bfr = *(const bh8*)(w1P + ((size_t)(nt * 4 + ks) * 64 + l) * 8);
            c1[ni] = __builtin_amdgcn_mfma_f32_16x16x32_bf16(a[ks], bfr, c1[ni], 0, 0, 0);
        }
    }
    #pragma unroll
    for (int ni = 0; ni < 8; ++ni) {
        int nt = w * 8 + ni;
        int col = nt * 16 + (l & 15);
        int r0 = (l >> 4) * 4;
        #pragma unroll
        for (int reg = 0; reg < 4; ++reg)
            H[r0 + reg][col] = cvt1_bf16(gelu_fast(c1[ni][reg] + b1s[col]));
    }
    __syncthreads();

    f32x4 c2[2];
    c2[0] = (f32x4){0.f, 0.f, 0.f, 0.f};
    c2[1] = (f32x4){0.f, 0.f, 0.f, 0.f};
    const char* hb = (const char*)&H[0][0];
    #pragma unroll
    for (int ks2 = 0; ks2 < 16; ++ks2) {
        bh8 af = *(const bh8*)(hb + (l & 15) * 1040 + ks2 * 64 + (l >> 4) * 16);
        #pragma unroll
        for (int i = 0; i < 2; ++i) {
            int nt2 = w * 2 + i;
            bh8 bfr = *(const bh8*)(w2P + ((size_t)(nt2 * 16 + ks2) * 64 + l) * 8);
            c2[i] = __builtin_amdgcn_mfma_f32_16x16x32_bf16(af, bfr, c2[i], 0, 0, 0);
        }
    }
    #pragma unroll
    for (int i = 0; i < 2; ++i) {
        int col = (w * 2 + i) * 16 + (l & 15);
        int r0 = (l >> 4) * 4;
        #pragma unroll
        for (int reg = 0; reg < 4; ++reg) oo[r0 + reg][col] = c2[i][reg] + b2s[col];
    }
    __syncthreads();

    #pragma unroll
    for (int rr = 0; rr < 4; ++rr) {
        int r = w * 4 + rr;
        float v0 = oo[r][l], v1 = oo[r][l + 64];
        float s = v0 + v1, sq = v0 * v0 + v1 * v1;
        #pragma unroll
        for (int m = 32; m > 0; m >>= 1) {
            s  += __shfl_xor(s, m, 64);
            sq += __shfl_xor(sq, m, 64);
        }
        float mu  = s * (1.0f / 128.0f);
        float var = sq * (1.0f / 128.0f) - mu * mu;
        float rs  = rsqrtf(var + 1e-5f);
        size_t ob = (rowbase + r) * 128;
        outp[ob + l]      = (v0 - mu) * rs * g2s[l]      + bt2s[l]      + xr[r][l];
        outp[ob + l + 64] = (v1 - mu) * rs * g2s[l + 64] + bt2s[l + 64] + xr[r][l + 64];
    }
}

// ---------------------------------------------------------------------------
extern "C" void kernel_launch(void* const* d_in, const int* in_sizes, int n_in,
                              void* d_out, int out_size, void* d_ws, size_t ws_size,
                              hipStream_t stream) {
    const float* x      = (const float*)d_in[0];
    const float* I      = (const float*)d_in[1];
    const float* IX     = (const float*)d_in[2];
    const float* IY     = (const float*)d_in[3];
    const float* IT     = (const float*)d_in[4];
    const float* w_idx  = (const float*)d_in[5];
    const float* b_idx  = (const float*)d_in[6];
    const float* w_proj = (const float*)d_in[7];
    const float* b_proj = (const float*)d_in[8];
    const float* w_mask = (const float*)d_in[9];
    const float* b_mask = (const float*)d_in[10];
    const float* g1     = (const float*)d_in[11];
    const float* beta1  = (const float*)d_in[12];
    const float* w_mlp1 = (const float*)d_in[13];
    const float* b_mlp1 = (const float*)d_in[14];
    const float* w_mlp2 = (const float*)d_in[15];
    const float* b_mlp2 = (const float*)d_in[16];
    const float* g2     = (const float*)d_in[17];
    const float* beta2  = (const float*)d_in[18];
    float* out = (float*)d_out;

    float* ws = (float*)d_ws;
    ushort* catPh  = (ushort*)ws;                  // 49152 us -> 24576 f
    ushort* catPm  = (ushort*)(ws + 24576);        // 49152 us -> 49152 f
    ushort* catPl  = (ushort*)(ws + 49152);        // 49152 us -> 73728 f
    ushort* w_projP = (ushort*)(ws + 73728);       // 8192 us  -> 77824
    ushort* w1P     = (ushort*)(ws + 77824);       // 65536 us -> 110592
    ushort* w2P     = (ushort*)(ws + 110592);      // 65536 us -> 143360
    float*  maskw   = ws + 143360;                 // 1048576 f -> 1191936
    uint*   meta    = (uint*)(ws + 1191936);       // 4194304 w -> 5386240
    uint4*  T1      = (uint4*)(ws + 5386240);      // 2097152 u4 -> 13774848
    ushort* T2      = (ushort*)(ws + 13774848);    // 2097152 us -> 14823424 (59MB)

    kT_pack<<<92, 256, 0, stream>>>(w_idx, w_mask, w_proj, w_mlp1, w_mlp2,
                                    catPh, catPm, catPl, w_projP, w1P, w2P);
    k01<<<2560, 256, 0, stream>>>(x, catPh, catPm, catPl, b_idx, b_mask,
                                  maskw, meta, I, IX, IY, IT, T1, T2);
    k2_rects<<<8192, 256, 0, stream>>>(T1, T2, meta, w_projP, b_proj, maskw,
                                       g1, beta1, out);
    k4_mlp<<<1024, 256, 0, stream>>>(out, w1P, b_mlp1, w2P, b_mlp2, g2, beta2, out);
}

// Round 10
// 84.545 us; speedup vs baseline: 1.1234x; 1.0249x over previous
//
#include <hip/hip_runtime.h>
#include <hip/hip_bf16.h>
#include <hip/hip_fp16.h>
#include <math.h>

#define BB   8
#define DD   1024

typedef short bh8 __attribute__((ext_vector_type(8)));
typedef float f32x4 __attribute__((ext_vector_type(4)));
typedef _Float16 h2f __attribute__((ext_vector_type(2)));

__device__ __forceinline__ ushort f2bf(float f) {
    uint u = __builtin_bit_cast(uint, f);
    u += 0x7fffu + ((u >> 16) & 1u);
    return (ushort)(u >> 16);
}
__device__ __forceinline__ float asf(uint u)  { return __builtin_bit_cast(float, u); }
__device__ __forceinline__ float bflo(uint u) { return __builtin_bit_cast(float, u << 16); }
__device__ __forceinline__ float bfhi(uint u) { return __builtin_bit_cast(float, u & 0xffff0000u); }
__device__ __forceinline__ uint  pkh(float a, float b) {
    return __builtin_bit_cast(uint, __builtin_amdgcn_cvt_pkrtz(a, b));
}
__device__ __forceinline__ h2f ash2f(uint u) { return __builtin_bit_cast(h2f, u); }

#if __has_builtin(__builtin_amdgcn_fdot2)
__device__ __forceinline__ float fdot2h(h2f a, h2f b, float c) {
    return __builtin_amdgcn_fdot2(a, b, c, false);
}
#else
__device__ __forceinline__ float fdot2h(h2f a, h2f b, float c) {
    return fmaf((float)a.x, (float)b.x, fmaf((float)a.y, (float)b.y, c));
}
#endif

// hardware packed f32->bf16 RTNE (no builtin on gfx950; asm per guide recipe)
__device__ __forceinline__ uint cvtpk_bf16(float a, float b) {
    uint r;
    asm("v_cvt_pk_bf16_f32 %0, %1, %2" : "=v"(r) : "v"(a), "v"(b));
    return r;
}
__device__ __forceinline__ ushort cvt1_bf16(float a) {
    uint r;
    asm("v_cvt_pk_bf16_f32 %0, %1, %2" : "=v"(r) : "v"(a), "v"(a));
    return (ushort)r;
}

// overflow-safe tanh-form gelu via exp2 + rcp
__device__ __forceinline__ float gelu_fast(float x) {
    float x2 = x * x;
#if __has_builtin(__builtin_amdgcn_exp2f)
    float e = __builtin_amdgcn_exp2f(x * fmaf(x2, -0.20588652f, -2.3022082f));
#else
    float e = __expf(-(1.5957691216f * x + 0.14270963f * x * x2));
#endif
    return x * __builtin_amdgcn_rcpf(1.0f + e);
}
__device__ __forceinline__ float sig63(float v) {
    return 63.0f * __builtin_amdgcn_rcpf(1.0f + __expf(-v));
}

// ---------------------------------------------------------------------------
// kT: ALL weight preprocessing (3-way split w_cat + proj/mlp fragment packs).
// ---------------------------------------------------------------------------
__global__ __launch_bounds__(256) void kT_pack(
    const float* __restrict__ w_idx, const float* __restrict__ w_mask,
    const float* __restrict__ w_proj, const float* __restrict__ w1,
    const float* __restrict__ w2,
    ushort* __restrict__ catPh, ushort* __restrict__ catPm,
    ushort* __restrict__ catPl,
    ushort* __restrict__ w_projP, ushort* __restrict__ w1P,
    ushort* __restrict__ w2P)
{
    int bid = blockIdx.x, t = threadIdx.x;
    if (bid < 24) {
        int gid = bid * 256 + t;                  // [0,6144)
        int l = gid & 63, ks = (gid >> 6) & 7, nt = gid >> 9;
        int n = nt * 16 + (l & 15);
        int kbase = ks * 32 + ((l >> 4) << 3);
        const float* src = (n < 64) ? (w_idx + (size_t)n * 256)
                                    : (w_mask + (size_t)(n - 64) * 256);
        ushort* dh = catPh + (size_t)gid * 8;
        ushort* dm = catPm + (size_t)gid * 8;
        ushort* dl = catPl + (size_t)gid * 8;
        #pragma unroll
        for (int j = 0; j < 8; ++j) {
            float v = src[kbase + j];
            ushort h = f2bf(v);
            float hf = __builtin_bit_cast(float, (uint)h << 16);
            float r1 = v - hf;
            ushort m = f2bf(r1); float mf = __builtin_bit_cast(float, (uint)m << 16);
            ushort lo = f2bf(r1 - mf);
            dh[j] = h; dm[j] = m; dl[j] = lo;
        }
    } else if (bid < 28) {               // w_proj (128,64): B[k=c][n=dch]
        int g = (bid - 24) * 256 + t;    // [0,1024)
        int nt = g >> 7, ks = (g >> 6) & 1, l = g & 63;
        int n = nt * 16 + (l & 15), k0 = ks * 32 + (l >> 4) * 8;
        ushort* dst = w_projP + (size_t)g * 8;
        #pragma unroll
        for (int j = 0; j < 8; ++j) dst[j] = f2bf(w_proj[n * 64 + k0 + j]);
    } else if (bid < 60) {               // w_mlp1 (512,128): B[k][n]
        int g = (bid - 28) * 256 + t;    // [0,8192)
        int nt = g >> 8, ks = (g >> 6) & 3, l = g & 63;
        int n = nt * 16 + (l & 15), k0 = ks * 32 + (l >> 4) * 8;
        ushort* dst = w1P + (size_t)g * 8;
        #pragma unroll
        for (int j = 0; j < 8; ++j) dst[j] = f2bf(w1[n * 128 + k0 + j]);
    } else {                             // w_mlp2 (128,512): B[k][n]
        int g = (bid - 60) * 256 + t;    // [0,8192)
        int nt = g >> 10, ks = (g >> 6) & 15, l = g & 63;
        int n = nt * 16 + (l & 15), k0 = ks * 32 + (l >> 4) * 8;
        ushort* dst = w2P + (size_t)g * 8;
        #pragma unroll
        for (int j = 0; j < 8; ++j) dst[j] = f2bf(w2[n * 512 + k0 + j]);
    }
}

// ---------------------------------------------------------------------------
// k01: fat kernel (R5 proven layout; meta replaced by slim coords).
//  blocks [0,2048)    : k1 texture coefficients, 16 channels/block
//  blocks [2048,2560) : k0 via MFMA (3-way bf16 split) + coords/softmax
//                       epilogue. coords = 4 post-sigmoid floats per unit
//                       (2 MB total vs meta's 16.8 MB) — k2 re-expands.
// ---------------------------------------------------------------------------
__global__ __launch_bounds__(256) void k01(
    const float* __restrict__ x,
    const ushort* __restrict__ catPh, const ushort* __restrict__ catPm,
    const ushort* __restrict__ catPl,
    const float* __restrict__ b_idx, const float* __restrict__ b_mask,
    float* __restrict__ maskw, float* __restrict__ coords,
    const float* __restrict__ I, const float* __restrict__ IX,
    const float* __restrict__ IY, const float* __restrict__ IT,
    uint4* __restrict__ T1, ushort* __restrict__ T2)
{
    __shared__ __align__(16) float sf[6528];      // 26112 B
    int t = threadIdx.x;
    int bid = blockIdx.x;

    if (bid >= 2048) {
        // ---------------- k0: coords + mask via MFMA ----------------
        float* sOut = sf;                          // [16][193] = 3088 f
        size_t rowbase = (size_t)(bid - 2048) * 16;
        int w = t >> 6, l = t & 63;

        f32x4 acc[3];
        acc[0] = (f32x4){0.f,0.f,0.f,0.f};
        acc[1] = (f32x4){0.f,0.f,0.f,0.f};
        acc[2] = (f32x4){0.f,0.f,0.f,0.f};
        const float* xr = x + (rowbase + (size_t)(l & 15)) * 256 + ((l >> 4) << 3);

        #pragma unroll
        for (int half = 0; half < 2; ++half) {
            bh8 Ah[4], Am[4], Al[4];
            #pragma unroll
            for (int k4 = 0; k4 < 4; ++k4) {
                int ks = half * 4 + k4;
                float4 v0 = *(const float4*)(xr + ks * 32);
                float4 v1 = *(const float4*)(xr + ks * 32 + 4);
                uint4 uh, um, ul;
                uh.x = cvtpk_bf16(v0.x, v0.y);
                uh.y = cvtpk_bf16(v0.z, v0.w);
                uh.z = cvtpk_bf16(v1.x, v1.y);
                uh.w = cvtpk_bf16(v1.z, v1.w);
                float r0a = v0.x - bflo(uh.x), r0b = v0.y - bfhi(uh.x);
                float r0c = v0.z - bflo(uh.y), r0d = v0.w - bfhi(uh.y);
                float r1a = v1.x - bflo(uh.z), r1b = v1.y - bfhi(uh.z);
                float r1c = v1.z - bflo(uh.w), r1d = v1.w - bfhi(uh.w);
                um.x = cvtpk_bf16(r0a, r0b);
                um.y = cvtpk_bf16(r0c, r0d);
                um.z = cvtpk_bf16(r1a, r1b);
                um.w = cvtpk_bf16(r1c, r1d);
                ul.x = cvtpk_bf16(r0a - bflo(um.x), r0b - bfhi(um.x));
                ul.y = cvtpk_bf16(r0c - bflo(um.y), r0d - bfhi(um.y));
                ul.z = cvtpk_bf16(r1a - bflo(um.z), r1b - bfhi(um.z));
                ul.w = cvtpk_bf16(r1c - bflo(um.w), r1d - bfhi(um.w));
                Ah[k4] = __builtin_bit_cast(bh8, uh);
                Am[k4] = __builtin_bit_cast(bh8, um);
                Al[k4] = __builtin_bit_cast(bh8, ul);
            }
            #pragma unroll
            for (int ntl = 0; ntl < 3; ++ntl) {
                int nt = w * 3 + ntl;
                #pragma unroll
                for (int k4 = 0; k4 < 4; ++k4) {
                    int ks = half * 4 + k4;
                    size_t fo = ((size_t)(nt * 8 + ks) * 64 + l) * 8;
                    bh8 bh = *(const bh8*)(catPh + fo);
                    bh8 bm = *(const bh8*)(catPm + fo);
                    bh8 bl = *(const bh8*)(catPl + fo);
                    acc[ntl] = __builtin_amdgcn_mfma_f32_16x16x32_bf16(Ah[k4], bh, acc[ntl], 0, 0, 0);
                    acc[ntl] = __builtin_amdgcn_mfma_f32_16x16x32_bf16(Ah[k4], bm, acc[ntl], 0, 0, 0);
                    acc[ntl] = __builtin_amdgcn_mfma_f32_16x16x32_bf16(Am[k4], bh, acc[ntl], 0, 0, 0);
                    acc[ntl] = __builtin_amdgcn_mfma_f32_16x16x32_bf16(Ah[k4], bl, acc[ntl], 0, 0, 0);
                    acc[ntl] = __builtin_amdgcn_mfma_f32_16x16x32_bf16(Al[k4], bh, acc[ntl], 0, 0, 0);
                    acc[ntl] = __builtin_amdgcn_mfma_f32_16x16x32_bf16(Am[k4], bm, acc[ntl], 0, 0, 0);
                }
            }
        }
        {
            int r0 = (l >> 4) * 4, cbase = w * 48 + (l & 15);
            #pragma unroll
            for (int ntl = 0; ntl < 3; ++ntl)
                #pragma unroll
                for (int reg = 0; reg < 4; ++reg)
                    sOut[(r0 + reg) * 193 + cbase + ntl * 16] = acc[ntl][reg];
        }
        __syncthreads();

        // coords epilogue: 16 rows x 16 units = 256 threads, one float4 each
        {
            int row = t >> 4, u = t & 15, br = u >> 3, nr = u & 7;
            const float* so = sOut + row * 193;
            int c0 = br * 32 + nr * 4;
            float4 co;
            co.x = sig63(so[c0 + 0] + b_idx[c0 + 0]);
            co.y = sig63(so[c0 + 1] + b_idx[c0 + 1]);
            co.z = sig63(so[c0 + 2] + b_idx[c0 + 2]);
            co.w = sig63(so[c0 + 3] + b_idx[c0 + 3]);
            *(float4*)(coords + (((rowbase + row) * 16) + (size_t)u) * 4) = co;
        }
        // softmax epilogue: 16 rows x (2 br x 8 g) = 256 threads
        {
            int row = t >> 4, br = (t >> 3) & 1, g = t & 7;
            const float* so = sOut + row * 193 + 64;
            float lg[8];
            float mx = -1e30f;
            #pragma unroll
            for (int nr = 0; nr < 8; ++nr) {
                int idx = br * 64 + nr * 8 + g;
                lg[nr] = so[idx] + b_mask[idx];
                mx = fmaxf(mx, lg[nr]);
            }
            float s = 0.f;
            #pragma unroll
            for (int nr = 0; nr < 8; ++nr) { lg[nr] = __expf(lg[nr] - mx); s += lg[nr]; }
            float inv = __builtin_amdgcn_rcpf(s);
            #pragma unroll
            for (int nr = 0; nr < 8; ++nr)
                maskw[(rowbase + row) * 128 + br * 64 + nr * 8 + g] = lg[nr] * inv;
        }
    } else {
        // ---------------- k1: 9-coeff texture, 16 channels/block ------------
        int chunk = bid & 3, h = (bid >> 2) & 63, b = bid >> 8;
        int hp = h > 0 ? h - 1 : 0;
        int cb = chunk * 16;
        size_t inb  = (size_t)b * 262144 + (size_t)h  * 64;
        size_t inbp = (size_t)b * 262144 + (size_t)hp * 64;

        {
            int c = t >> 4, w4 = (t & 15) << 2;
            size_t o = (size_t)(cb + c) * 4096 + w4;
            int so = c * 68 + w4;
            *(float4*)(sf + 0 * 1088 + so) = *(const float4*)(I  + inb  + o);
            *(float4*)(sf + 1 * 1088 + so) = *(const float4*)(I  + inbp + o);
            *(float4*)(sf + 2 * 1088 + so) = *(const float4*)(IX + inb  + o);
            *(float4*)(sf + 3 * 1088 + so) = *(const float4*)(IY + inb  + o);
            *(float4*)(sf + 4 * 1088 + so) = *(const float4*)(IY + inbp + o);
            *(float4*)(sf + 5 * 1088 + so) = *(const float4*)(IT + inb  + o);
        }
        __syncthreads();

        #pragma unroll
        for (int i = 0; i < 4; ++i) {
            int idx = i * 256 + t; int w = idx >> 4, c = idx & 15;
            int wm = w > 0 ? w - 1 : 0;
            int rb = c * 68;
            float I00 = sf[rb + w],        I0m = sf[rb + wm];
            float Im0 = sf[1088 + rb + w], Imm = sf[1088 + rb + wm];
            float E1  = sf[2176 + rb + w]  - 0.5f * I00;
            float E1m = sf[2176 + rb + wm] - 0.5f * I0m;
            float E2  = sf[3264 + rb + w]  - 0.5f * I00;
            float E2m = sf[4352 + rb + w]  - 0.5f * Im0;
            float v0 = sf[5440 + rb + w];
            float v1 = -E1;
            float v2 = 0.5f * (E1 - E1m);
            float v3 = -E2;
            float v4 = 0.5f * (E2 - E2m);
            float v5 = I00;
            float v6 = 0.5f * (I0m - I00);
            float v7 = 0.5f * (Im0 - I00);
            float v8 = 0.25f * ((Imm - I0m) - (Im0 - I00));
            size_t pt = (((size_t)b * 4096) + (size_t)h * 64 + w) * 64 + (cb + c);
            uint4 o4;
            o4.x = pkh(v0, v1);
            o4.y = pkh(v2, v3);
            o4.z = pkh(v4, v5);
            o4.w = pkh(v6, v7);
            T1[pt] = o4;
            T2[pt] = (ushort)(pkh(v8, 0.f) & 0xffffu);
        }
    }
}

// ---------------------------------------------------------------------------
// k2: fused sampling + rects GEMM + gelu + mask-sum + LN1.  (round-5 proven
// structure; meta expanded in-prologue from slim coords — bit-identical math)
// ---------------------------------------------------------------------------
__global__ __launch_bounds__(256) void k2_rects(
    const uint4* __restrict__ T1, const ushort* __restrict__ T2,
    const float* __restrict__ coords,
    const ushort* __restrict__ w_projP, const float* __restrict__ b_proj,
    const float* __restrict__ maskw, const float* __restrict__ g1,
    const float* __restrict__ beta1, float* __restrict__ mid)
{
    __shared__ __align__(16) uint meta_lds[16][32];
    __shared__ __align__(16) float S_lds[16][68];
    __shared__ float mrow[128];
    __shared__ float outr[2][128];
    int bid = blockIdx.x;
    int b = bid & 7, d = bid >> 3;
    int t = threadIdx.x, w = t >> 6, l = t & 63;
    size_t tile = (size_t)b * DD + d;
    if (t < 64) {
        // expand coords -> meta words (same ops meta epilogue used to do)
        int u = t >> 2, c = t & 3;
        float4 co = *(const float4*)(coords + (tile * 16 + (size_t)u) * 4);
        float x1 = co.x, y1 = co.y, x2 = co.z, y2 = co.w;
        int X1 = (int)ceilf(x1); X1 = X1 < 1 ? 1 : (X1 > 63 ? 63 : X1);
        int X2 = (int)ceilf(x2); X2 = X2 < 1 ? 1 : (X2 > 63 ? 63 : X2);
        int Y1 = (int)ceilf(y1); Y1 = Y1 < 1 ? 1 : (Y1 > 63 ? 63 : Y1);
        int Y2 = (int)ceilf(y2); Y2 = Y2 < 1 ? 1 : (Y2 > 63 ? 63 : Y2);
        float dxa = (float)X1 - x1, dxb = (float)X2 - x2;
        float dya = (float)Y1 - y1, dyb = (float)Y2 - y2;
        int   Xc = (c & 1) ? X1 : X2;
        int   Yc = (c < 2) ? Y2 : Y1;
        float s  = (c == 0 || c == 3) ? 1.f : -1.f;
        float dx = (c & 1) ? dxa : dxb;
        float dy = (c < 2) ? dyb : dya;
        float dx2 = dx * dx, dy2 = dy * dy;
        uint pt = (uint)(Xc * 64 + Yc);
        uint4 wa, wb;
        wa.x = pt * 1024u;
        wa.y = pt * 128u;
        wa.z = pkh(s, s * dy);
        wa.w = pkh(s * dy2, s * dx);
        wb.x = pkh(s * dx2, s * dx * dy);
        wb.y = pkh(s * dx * dy2, s * dx2 * dy);
        wb.z = __builtin_bit_cast(uint, s * dx2 * dy2);
        wb.w = 0u;
        *(uint4*)&meta_lds[u][c * 8 + 0] = wa;
        *(uint4*)&meta_lds[u][c * 8 + 4] = wb;
    }
    if (t >= 128) mrow[t - 128] = maskw[tile * 128 + (t - 128)];

    bh8 bf[2][2];
    #pragma unroll
    for (int ni = 0; ni < 2; ++ni) {
        int nt = w * 2 + ni;
        #pragma unroll
        for (int ks = 0; ks < 2; ++ks)
            bf[ni][ks] = *(const bh8*)(w_projP + ((size_t)(nt * 2 + ks) * 64 + l) * 8);
    }
    __syncthreads();
    const char* t1b = ((const char*)T1) + ((size_t)b << 22) + (size_t)(l * 16);
    const char* t2b = ((const char*)T2) + ((size_t)b << 19) + (size_t)(l * 2);

    int m0 = w * 4;
    uint4 q[2][4]; ushort e8[2][4];
    #pragma unroll
    for (int g = 0; g < 2; ++g) {
        #pragma unroll
        for (int c = 0; c < 4; ++c) {
            uint o1 = __builtin_amdgcn_readfirstlane(meta_lds[m0 + g][c * 8 + 0]);
            uint o2 = __builtin_amdgcn_readfirstlane(meta_lds[m0 + g][c * 8 + 1]);
            q[g][c]  = *(const uint4*)(t1b + o1);
            e8[g][c] = *(const ushort*)(t2b + o2);
        }
    }
    #pragma unroll
    for (int rr = 0; rr < 4; ++rr) {
        int m = m0 + rr;
        int cur = rr & 1;
        uint4 qc[4]; ushort ec[4];
        #pragma unroll
        for (int c = 0; c < 4; ++c) { qc[c] = q[cur][c]; ec[c] = e8[cur][c]; }
        if (rr < 2) {
            int mn = m + 2;
            #pragma unroll
            for (int c = 0; c < 4; ++c) {
                uint o1 = __builtin_amdgcn_readfirstlane(meta_lds[mn][c * 8 + 0]);
                uint o2 = __builtin_amdgcn_readfirstlane(meta_lds[mn][c * 8 + 1]);
                q[cur][c]  = *(const uint4*)(t1b + o1);
                e8[cur][c] = *(const ushort*)(t2b + o2);
            }
        }
        float acc0 = 0.f, acc1 = 0.f;
        #pragma unroll
        for (int c = 0; c < 4; ++c) {
            uint cz = meta_lds[m][c * 8 + 2], cw = meta_lds[m][c * 8 + 3];
            uint bx = meta_lds[m][c * 8 + 4], by = meta_lds[m][c * 8 + 5];
            float bz = asf(meta_lds[m][c * 8 + 6]);
            float ev = __half2float(__builtin_bit_cast(__half, ec[c]));
            float cv = bz * ev;
            cv = fdot2h(ash2f(by), ash2f(qc[c].w), cv);
            cv = fdot2h(ash2f(bx), ash2f(qc[c].z), cv);
            cv = fdot2h(ash2f(cw), ash2f(qc[c].y), cv);
            cv = fdot2h(ash2f(cz), ash2f(qc[c].x), cv);
            if (c & 1) acc1 += cv; else acc0 += cv;
        }
        S_lds[m][l] = acc0 + acc1;
    }
    __syncthreads();

    int am = l & 15, q2 = l >> 4;
    bh8 a0, a1;
    {
        float4 va = *(const float4*)&S_lds[am][q2 * 8];
        float4 vb = *(const float4*)&S_lds[am][q2 * 8 + 4];
        uint4 ua;
        ua.x = cvtpk_bf16(va.x, va.y);
        ua.y = cvtpk_bf16(va.z, va.w);
        ua.z = cvtpk_bf16(vb.x, vb.y);
        ua.w = cvtpk_bf16(vb.z, vb.w);
        a0 = __builtin_bit_cast(bh8, ua);
        float4 vc = *(const float4*)&S_lds[am][32 + q2 * 8];
        float4 vd = *(const float4*)&S_lds[am][32 + q2 * 8 + 4];
        uint4 ub;
        ub.x = cvtpk_bf16(vc.x, vc.y);
        ub.y = cvtpk_bf16(vc.z, vc.w);
        ub.z = cvtpk_bf16(vd.x, vd.y);
        ub.w = cvtpk_bf16(vd.z, vd.w);
        a1 = __builtin_bit_cast(bh8, ub);
    }
    f32x4 cc[2];
    cc[0] = (f32x4){0.f, 0.f, 0.f, 0.f};
    cc[1] = (f32x4){0.f, 0.f, 0.f, 0.f};
    cc[0] = __builtin_amdgcn_mfma_f32_16x16x32_bf16(a0, bf[0][0], cc[0], 0, 0, 0);
    cc[0] = __builtin_amdgcn_mfma_f32_16x16x32_bf16(a1, bf[0][1], cc[0], 0, 0, 0);
    cc[1] = __builtin_amdgcn_mfma_f32_16x16x32_bf16(a0, bf[1][0], cc[1], 0, 0, 0);
    cc[1] = __builtin_amdgcn_mfma_f32_16x16x32_bf16(a1, bf[1][1], cc[1], 0, 0, 0);

    int cl = l & 15;
    #pragma unroll
    for (int ni = 0; ni < 2; ++ni) {
        int nt = w * 2 + ni;
        int col = nt * 16 + cl;
        float bpv = b_proj[col];
        float p = 0.f;
        #pragma unroll
        for (int reg = 0; reg < 4; ++reg) {
            int r = q2 * 4 + reg;
            float v = cc[ni][reg] + bpv;
            p += gelu_fast(v) * mrow[(r >> 3) * 64 + (r & 7) * 8 + nt];
        }
        p += __shfl_xor(p, 16, 64);
        if (q2 == 0) outr[0][col] = p;
        else if (q2 == 2) outr[1][col] = p;
    }
    __syncthreads();

    if (w < 2) {
        float v0 = outr[w][l], v1 = outr[w][l + 64];
        float s = v0 + v1, sq = v0 * v0 + v1 * v1;
        #pragma unroll
        for (int mm = 32; mm > 0; mm >>= 1) {
            s  += __shfl_xor(s, mm, 64);
            sq += __shfl_xor(sq, mm, 64);
        }
        float mu  = s * (1.0f / 128.0f);
        float var = sq * (1.0f / 128.0f) - mu * mu;
        float rs  = rsqrtf(var + 1e-5f);
        size_t ob = (tile * 2 + w) * 128;
        mid[ob + l]      = (v0 - mu) * rs * g1[l]      + beta1[l];
        mid[ob + l + 64] = (v1 - mu) * rs * g1[l + 64] + beta1[l + 64];
    }
}

// ---------------------------------------------------------------------------
// k4: MLP 128->512(gelu)->128 via MFMA, 16 rows/block, + LN2 + residual.
// ---------------------------------------------------------------------------
__global__ __launch_bounds__(256) void k4_mlp(
    const float* __restrict__ mid, const ushort* __restrict__ w1P,
    const float* __restrict__ b1, const ushort* __restrict__ w2P,
    const float* __restrict__ b2, const float* __restrict__ g2,
    const float* __restrict__ beta2, float* __restrict__ outp)
{
    __shared__ float xr[16][132];
    __shared__ __align__(16) ushort Af[4][64][8];
    __shared__ __align__(16) ushort H[16][520];
    __shared__ float oo[16][128];
    __shared__ float b1s[512];
    __shared__ float b2s[128], g2s[128], bt2s[128];
    int t = threadIdx.x, w = t >> 6, l = t & 63;
    int bid = blockIdx.x;
    int mt = (bid & 7) * 128 + (bid >> 3);   // XCD-local by batch
    size_t rowbase = (size_t)mt * 16;

    {
        const float4* mg = (const float4*)(mid + rowbase * 128);
        #pragma unroll
        for (int i4 = 0; i4 < 2; ++i4) {
            int i = i4 * 256 + t;
            float4 v = mg[i];
            *(float4*)(&xr[i >> 5][(i & 31) * 4]) = v;
        }
    }
    for (int i = t; i < 512; i += 256) b1s[i] = b1[i];
    if (t < 128) { b2s[t] = b2[t]; g2s[t] = g2[t]; bt2s[t] = beta2[t]; }
    __syncthreads();

    {
        int ks = t >> 6, m = l & 15, c0 = ks * 32 + (l >> 4) * 8;
        uint* dst = (uint*)&Af[ks][l][0];
        #pragma unroll
        for (int j = 0; j < 4; ++j)
            dst[j] = cvtpk_bf16(xr[m][c0 + 2 * j], xr[m][c0 + 2 * j + 1]);
    }
    __syncthreads();

    f32x4 c1[8];
    #pragma unroll
    for (int i = 0; i < 8; ++i) c1[i] = (f32x4){0.f, 0.f, 0.f, 0.f};
    bh8 a[4];
    #pragma unroll
    for (int ks = 0; ks < 4; ++ks) a[ks] = *(const bh8*)&Af[ks][l][0];
    #pragma unroll
    for (int ni = 0; ni < 8; ++ni) {
        int nt = w * 8 + ni;
        #pragma unroll
        for (int ks = 0; ks < 4; ++ks) {
            bh8 bfr = *(const bh8*)(w1P + ((size_t)(nt * 4 + ks) * 64 + l) * 8);
            c1[ni] = __builtin_amdgcn_mfma_f32_16x16x32_bf16(a[ks], bfr, c1[ni], 0, 0, 0);
        }
    }
    #pragma unroll
    for (int ni = 0; ni < 8; ++ni) {
        int nt = w * 8 + ni;
        int col = nt * 16 + (l & 15);
        int r0 = (l >> 4) * 4;
        #pragma unroll
        for (int reg = 0; reg < 4; ++reg)
            H[r0 + reg][col] = cvt1_bf16(gelu_fast(c1[ni][reg] + b1s[col]));
    }
    __syncthreads();

    f32x4 c2[2];
    c2[0] = (f32x4){0.f, 0.f, 0.f, 0.f};
    c2[1] = (f32x4){0.f, 0.f, 0.f, 0.f};
    const char* hb = (const char*)&H[0][0];
    #pragma unroll
    for (int ks2 = 0; ks2 < 16; ++ks2) {
        bh8 af = *(const bh8*)(hb + (l & 15) * 1040 + ks2 * 64 + (l >> 4) * 16);
        #pragma unroll
        for (int i = 0; i < 2; ++i) {
            int nt2 = w * 2 + i;
            bh8 bfr = *(const bh8*)(w2P + ((size_t)(nt2 * 16 + ks2) * 64 + l) * 8);
            c2[i] = __builtin_amdgcn_mfma_f32_16x16x32_bf16(af, bfr, c2[i], 0, 0, 0);
        }
    }
    #pragma unroll
    for (int i = 0; i < 2; ++i) {
        int col = (w * 2 + i) * 16 + (l & 15);
        int r0 = (l >> 4) * 4;
        #pragma unroll
        for (int reg = 0; reg < 4; ++reg) oo[r0 + reg][col] = c2[i][reg] + b2s[col];
    }
    __syncthreads();

    #pragma unroll
    for (int rr = 0; rr < 4; ++rr) {
        int r = w * 4 + rr;
        float v0 = oo[r][l], v1 = oo[r][l + 64];
        float s = v0 + v1, sq = v0 * v0 + v1 * v1;
        #pragma unroll
        for (int m = 32; m > 0; m >>= 1) {
            s  += __shfl_xor(s, m, 64);
            sq += __shfl_xor(sq, m, 64);
        }
        float mu  = s * (1.0f / 128.0f);
        float var = sq * (1.0f / 128.0f) - mu * mu;
        float rs  = rsqrtf(var + 1e-5f);
        size_t ob = (rowbase + r) * 128;
        outp[ob + l]      = (v0 - mu) * rs * g2s[l]      + bt2s[l]      + xr[r][l];
        outp[ob + l + 64] = (v1 - mu) * rs * g2s[l + 64] + bt2s[l + 64] + xr[r][l + 64];
    }
}

// ---------------------------------------------------------------------------
extern "C" void kernel_launch(void* const* d_in, const int* in_sizes, int n_in,
                              void* d_out, int out_size, void* d_ws, size_t ws_size,
                              hipStream_t stream) {
    const float* x      = (const float*)d_in[0];
    const float* I      = (const float*)d_in[1];
    const float* IX     = (const float*)d_in[2];
    const float* IY     = (const float*)d_in[3];
    const float* IT     = (const float*)d_in[4];
    const float* w_idx  = (const float*)d_in[5];
    const float* b_idx  = (const float*)d_in[6];
    const float* w_proj = (const float*)d_in[7];
    const float* b_proj = (const float*)d_in[8];
    const float* w_mask = (const float*)d_in[9];
    const float* b_mask = (const float*)d_in[10];
    const float* g1     = (const float*)d_in[11];
    const float* beta1  = (const float*)d_in[12];
    const float* w_mlp1 = (const float*)d_in[13];
    const float* b_mlp1 = (const float*)d_in[14];
    const float* w_mlp2 = (const float*)d_in[15];
    const float* b_mlp2 = (const float*)d_in[16];
    const float* g2     = (const float*)d_in[17];
    const float* beta2  = (const float*)d_in[18];
    float* out = (float*)d_out;

    float* ws = (float*)d_ws;
    ushort* catPh  = (ushort*)ws;                  // 49152 us -> 24576 f
    ushort* catPm  = (ushort*)(ws + 24576);        // 49152 us -> 49152 f
    ushort* catPl  = (ushort*)(ws + 49152);        // 49152 us -> 73728 f
    ushort* w_projP = (ushort*)(ws + 73728);       // 8192 us  -> 77824
    ushort* w1P     = (ushort*)(ws + 77824);       // 65536 us -> 110592
    ushort* w2P     = (ushort*)(ws + 110592);      // 65536 us -> 143360
    float*  maskw   = ws + 143360;                 // 1048576 f -> 1191936
    float*  coords  = ws + 1191936;                // 524288 f  -> 1716224
    uint4*  T1      = (uint4*)(ws + 1716224);      // 2097152 u4 -> 10104832
    ushort* T2      = (ushort*)(ws + 10104832);    // 2097152 us -> 11153408 (45MB)

    kT_pack<<<92, 256, 0, stream>>>(w_idx, w_mask, w_proj, w_mlp1, w_mlp2,
                                    catPh, catPm, catPl, w_projP, w1P, w2P);
    k01<<<2560, 256, 0, stream>>>(x, catPh, catPm, catPl, b_idx, b_mask,
                                  maskw, coords, I, IX, IY, IT, T1, T2);
    k2_rects<<<8192, 256, 0, stream>>>(T1, T2, coords, w_projP, b_proj, maskw,
                                       g1, beta1, out);
    k4_mlp<<<1024, 256, 0, stream>>>(out, w1P, b_mlp1, w2P, b_mlp2, g2, beta2, out);
}

// Round 11
// 81.408 us; speedup vs baseline: 1.1667x; 1.0385x over previous
//
#include <hip/hip_runtime.h>
#include <hip/hip_bf16.h>
#include <hip/hip_fp16.h>
#include <math.h>

#define BB   8
#define DD   1024

typedef short bh8 __attribute__((ext_vector_type(8)));
typedef float f32x4 __attribute__((ext_vector_type(4)));
typedef _Float16 h2f __attribute__((ext_vector_type(2)));

__device__ __forceinline__ ushort f2bf(float f) {
    uint u = __builtin_bit_cast(uint, f);
    u += 0x7fffu + ((u >> 16) & 1u);
    return (ushort)(u >> 16);
}
__device__ __forceinline__ float asf(uint u)  { return __builtin_bit_cast(float, u); }
__device__ __forceinline__ float bflo(uint u) { return __builtin_bit_cast(float, u << 16); }
__device__ __forceinline__ float bfhi(uint u) { return __builtin_bit_cast(float, u & 0xffff0000u); }
__device__ __forceinline__ uint  pkh(float a, float b) {
    return __builtin_bit_cast(uint, __builtin_amdgcn_cvt_pkrtz(a, b));
}
__device__ __forceinline__ h2f ash2f(uint u) { return __builtin_bit_cast(h2f, u); }

#if __has_builtin(__builtin_amdgcn_fdot2)
__device__ __forceinline__ float fdot2h(h2f a, h2f b, float c) {
    return __builtin_amdgcn_fdot2(a, b, c, false);
}
#else
__device__ __forceinline__ float fdot2h(h2f a, h2f b, float c) {
    return fmaf((float)a.x, (float)b.x, fmaf((float)a.y, (float)b.y, c));
}
#endif

// hardware packed f32->bf16 RTNE (no builtin on gfx950; asm per guide recipe)
__device__ __forceinline__ uint cvtpk_bf16(float a, float b) {
    uint r;
    asm("v_cvt_pk_bf16_f32 %0, %1, %2" : "=v"(r) : "v"(a), "v"(b));
    return r;
}
__device__ __forceinline__ ushort cvt1_bf16(float a) {
    uint r;
    asm("v_cvt_pk_bf16_f32 %0, %1, %2" : "=v"(r) : "v"(a), "v"(a));
    return (ushort)r;
}

// overflow-safe tanh-form gelu via exp2 + rcp
__device__ __forceinline__ float gelu_fast(float x) {
    float x2 = x * x;
#if __has_builtin(__builtin_amdgcn_exp2f)
    float e = __builtin_amdgcn_exp2f(x * fmaf(x2, -0.20588652f, -2.3022082f));
#else
    float e = __expf(-(1.5957691216f * x + 0.14270963f * x * x2));
#endif
    return x * __builtin_amdgcn_rcpf(1.0f + e);
}
__device__ __forceinline__ float sig63(float v) {
    return 63.0f * __builtin_amdgcn_rcpf(1.0f + __expf(-v));
}

// ---------------------------------------------------------------------------
// kT: weight preprocessing + rowflag zeroing (bid 92).
// ---------------------------------------------------------------------------
__global__ __launch_bounds__(256) void kT_pack(
    const float* __restrict__ w_idx, const float* __restrict__ w_mask,
    const float* __restrict__ w_proj, const float* __restrict__ w1,
    const float* __restrict__ w2,
    ushort* __restrict__ catPh, ushort* __restrict__ catPm,
    ushort* __restrict__ catPl,
    ushort* __restrict__ w_projP, ushort* __restrict__ w1P,
    ushort* __restrict__ w2P, uint* __restrict__ rowflag)
{
    int bid = blockIdx.x, t = threadIdx.x;
    if (bid < 24) {
        int gid = bid * 256 + t;                  // [0,6144)
        int l = gid & 63, ks = (gid >> 6) & 7, nt = gid >> 9;
        int n = nt * 16 + (l & 15);
        int kbase = ks * 32 + ((l >> 4) << 3);
        const float* src = (n < 64) ? (w_idx + (size_t)n * 256)
                                    : (w_mask + (size_t)(n - 64) * 256);
        ushort* dh = catPh + (size_t)gid * 8;
        ushort* dm = catPm + (size_t)gid * 8;
        ushort* dl = catPl + (size_t)gid * 8;
        #pragma unroll
        for (int j = 0; j < 8; ++j) {
            float v = src[kbase + j];
            ushort h = f2bf(v);
            float hf = __builtin_bit_cast(float, (uint)h << 16);
            float r1 = v - hf;
            ushort m = f2bf(r1); float mf = __builtin_bit_cast(float, (uint)m << 16);
            ushort lo = f2bf(r1 - mf);
            dh[j] = h; dm[j] = m; dl[j] = lo;
        }
    } else if (bid < 28) {               // w_proj (128,64): B[k=c][n=dch]
        int g = (bid - 24) * 256 + t;    // [0,1024)
        int nt = g >> 7, ks = (g >> 6) & 1, l = g & 63;
        int n = nt * 16 + (l & 15), k0 = ks * 32 + (l >> 4) * 8;
        ushort* dst = w_projP + (size_t)g * 8;
        #pragma unroll
        for (int j = 0; j < 8; ++j) dst[j] = f2bf(w_proj[n * 64 + k0 + j]);
    } else if (bid < 60) {               // w_mlp1 (512,128): B[k][n]
        int g = (bid - 28) * 256 + t;    // [0,8192)
        int nt = g >> 8, ks = (g >> 6) & 3, l = g & 63;
        int n = nt * 16 + (l & 15), k0 = ks * 32 + (l >> 4) * 8;
        ushort* dst = w1P + (size_t)g * 8;
        #pragma unroll
        for (int j = 0; j < 8; ++j) dst[j] = f2bf(w1[n * 128 + k0 + j]);
    } else if (bid < 92) {               // w_mlp2 (128,512): B[k][n]
        int g = (bid - 60) * 256 + t;    // [0,8192)
        int nt = g >> 10, ks = (g >> 6) & 15, l = g & 63;
        int n = nt * 16 + (l & 15), k0 = ks * 32 + (l >> 4) * 8;
        ushort* dst = w2P + (size_t)g * 8;
        #pragma unroll
        for (int j = 0; j < 8; ++j) dst[j] = f2bf(w2[n * 512 + k0 + j]);
    } else {                             // zero rowflag (8*64 bytes)
        if (t < 128) rowflag[t] = 0u;
    }
}

// ---------------------------------------------------------------------------
// kA: k0 coords+mask via MFMA (3-way bf16 split), 512 blocks.
// Also flags which texture rows (X values) will be gathered, per batch.
// ---------------------------------------------------------------------------
__global__ __launch_bounds__(256) void kA_coords(
    const float* __restrict__ x,
    const ushort* __restrict__ catPh, const ushort* __restrict__ catPm,
    const ushort* __restrict__ catPl,
    const float* __restrict__ b_idx, const float* __restrict__ b_mask,
    float* __restrict__ maskw, float* __restrict__ coords,
    unsigned char* __restrict__ rowflag)
{
    __shared__ __align__(16) float sOut[16 * 193];
    int t = threadIdx.x;
    size_t rowbase = (size_t)blockIdx.x * 16;
    int w = t >> 6, l = t & 63;

    f32x4 acc[3];
    acc[0] = (f32x4){0.f,0.f,0.f,0.f};
    acc[1] = (f32x4){0.f,0.f,0.f,0.f};
    acc[2] = (f32x4){0.f,0.f,0.f,0.f};
    const float* xr = x + (rowbase + (size_t)(l & 15)) * 256 + ((l >> 4) << 3);

    #pragma unroll
    for (int half = 0; half < 2; ++half) {
        bh8 Ah[4], Am[4], Al[4];
        #pragma unroll
        for (int k4 = 0; k4 < 4; ++k4) {
            int ks = half * 4 + k4;
            float4 v0 = *(const float4*)(xr + ks * 32);
            float4 v1 = *(const float4*)(xr + ks * 32 + 4);
            uint4 uh, um, ul;
            uh.x = cvtpk_bf16(v0.x, v0.y);
            uh.y = cvtpk_bf16(v0.z, v0.w);
            uh.z = cvtpk_bf16(v1.x, v1.y);
            uh.w = cvtpk_bf16(v1.z, v1.w);
            float r0a = v0.x - bflo(uh.x), r0b = v0.y - bfhi(uh.x);
            float r0c = v0.z - bflo(uh.y), r0d = v0.w - bfhi(uh.y);
            float r1a = v1.x - bflo(uh.z), r1b = v1.y - bfhi(uh.z);
            float r1c = v1.z - bflo(uh.w), r1d = v1.w - bfhi(uh.w);
            um.x = cvtpk_bf16(r0a, r0b);
            um.y = cvtpk_bf16(r0c, r0d);
            um.z = cvtpk_bf16(r1a, r1b);
            um.w = cvtpk_bf16(r1c, r1d);
            ul.x = cvtpk_bf16(r0a - bflo(um.x), r0b - bfhi(um.x));
            ul.y = cvtpk_bf16(r0c - bflo(um.y), r0d - bfhi(um.y));
            ul.z = cvtpk_bf16(r1a - bflo(um.z), r1b - bfhi(um.z));
            ul.w = cvtpk_bf16(r1c - bflo(um.w), r1d - bfhi(um.w));
            Ah[k4] = __builtin_bit_cast(bh8, uh);
            Am[k4] = __builtin_bit_cast(bh8, um);
            Al[k4] = __builtin_bit_cast(bh8, ul);
        }
        #pragma unroll
        for (int ntl = 0; ntl < 3; ++ntl) {
            int nt = w * 3 + ntl;
            #pragma unroll
            for (int k4 = 0; k4 < 4; ++k4) {
                int ks = half * 4 + k4;
                size_t fo = ((size_t)(nt * 8 + ks) * 64 + l) * 8;
                bh8 bh = *(const bh8*)(catPh + fo);
                bh8 bm = *(const bh8*)(catPm + fo);
                bh8 bl = *(const bh8*)(catPl + fo);
                acc[ntl] = __builtin_amdgcn_mfma_f32_16x16x32_bf16(Ah[k4], bh, acc[ntl], 0, 0, 0);
                acc[ntl] = __builtin_amdgcn_mfma_f32_16x16x32_bf16(Ah[k4], bm, acc[ntl], 0, 0, 0);
                acc[ntl] = __builtin_amdgcn_mfma_f32_16x16x32_bf16(Am[k4], bh, acc[ntl], 0, 0, 0);
                acc[ntl] = __builtin_amdgcn_mfma_f32_16x16x32_bf16(Ah[k4], bl, acc[ntl], 0, 0, 0);
                acc[ntl] = __builtin_amdgcn_mfma_f32_16x16x32_bf16(Al[k4], bh, acc[ntl], 0, 0, 0);
                acc[ntl] = __builtin_amdgcn_mfma_f32_16x16x32_bf16(Am[k4], bm, acc[ntl], 0, 0, 0);
            }
        }
    }
    {
        int r0 = (l >> 4) * 4, cbase = w * 48 + (l & 15);
        #pragma unroll
        for (int ntl = 0; ntl < 3; ++ntl)
            #pragma unroll
            for (int reg = 0; reg < 4; ++reg)
                sOut[(r0 + reg) * 193 + cbase + ntl * 16] = acc[ntl][reg];
    }
    __syncthreads();

    // coords epilogue + row flags: 16 rows x 16 units = 256 threads
    {
        int row = t >> 4, u = t & 15, br = u >> 3, nr = u & 7;
        const float* so = sOut + row * 193;
        int c0 = br * 32 + nr * 4;
        float4 co;
        co.x = sig63(so[c0 + 0] + b_idx[c0 + 0]);
        co.y = sig63(so[c0 + 1] + b_idx[c0 + 1]);
        co.z = sig63(so[c0 + 2] + b_idx[c0 + 2]);
        co.w = sig63(so[c0 + 3] + b_idx[c0 + 3]);
        size_t tile = rowbase + row;
        *(float4*)(coords + (tile * 16 + (size_t)u) * 4) = co;
        // flag texture rows X1, X2 for this batch (idempotent byte stores)
        int bb = (int)(tile >> 10);
        int Xa = (int)ceilf(co.x); Xa = Xa < 1 ? 1 : (Xa > 63 ? 63 : Xa);
        int Xb = (int)ceilf(co.z); Xb = Xb < 1 ? 1 : (Xb > 63 ? 63 : Xb);
        rowflag[bb * 64 + Xa] = 1;
        rowflag[bb * 64 + Xb] = 1;
    }
    // softmax epilogue: 16 rows x (2 br x 8 g) = 256 threads
    {
        int row = t >> 4, br = (t >> 3) & 1, g = t & 7;
        const float* so = sOut + row * 193 + 64;
        float lg[8];
        float mx = -1e30f;
        #pragma unroll
        for (int nr = 0; nr < 8; ++nr) {
            int idx = br * 64 + nr * 8 + g;
            lg[nr] = so[idx] + b_mask[idx];
            mx = fmaxf(mx, lg[nr]);
        }
        float s = 0.f;
        #pragma unroll
        for (int nr = 0; nr < 8; ++nr) { lg[nr] = __expf(lg[nr] - mx); s += lg[nr]; }
        float inv = __builtin_amdgcn_rcpf(s);
        #pragma unroll
        for (int nr = 0; nr < 8; ++nr)
            maskw[(rowbase + row) * 128 + br * 64 + nr * 8 + g] = lg[nr] * inv;
    }
}

// ---------------------------------------------------------------------------
// kB: 9-coeff texture, 16 channels/block — only for FLAGGED rows.
// Unflagged (b,h) rows early-exit: their texture is never gathered.
// ---------------------------------------------------------------------------
__global__ __launch_bounds__(256) void kB_tex(
    const float* __restrict__ I, const float* __restrict__ IX,
    const float* __restrict__ IY, const float* __restrict__ IT,
    const unsigned char* __restrict__ rowflag,
    uint4* __restrict__ T1, ushort* __restrict__ T2)
{
    __shared__ __align__(16) float sf[6528];
    int t = threadIdx.x;
    int bid = blockIdx.x;
    int chunk = bid & 3, h = (bid >> 2) & 63, b = bid >> 8;
    if (rowflag[b * 64 + h] == 0) return;

    int hp = h > 0 ? h - 1 : 0;
    int cb = chunk * 16;
    size_t inb  = (size_t)b * 262144 + (size_t)h  * 64;
    size_t inbp = (size_t)b * 262144 + (size_t)hp * 64;

    {
        int c = t >> 4, w4 = (t & 15) << 2;
        size_t o = (size_t)(cb + c) * 4096 + w4;
        int so = c * 68 + w4;
        *(float4*)(sf + 0 * 1088 + so) = *(const float4*)(I  + inb  + o);
        *(float4*)(sf + 1 * 1088 + so) = *(const float4*)(I  + inbp + o);
        *(float4*)(sf + 2 * 1088 + so) = *(const float4*)(IX + inb  + o);
        *(float4*)(sf + 3 * 1088 + so) = *(const float4*)(IY + inb  + o);
        *(float4*)(sf + 4 * 1088 + so) = *(const float4*)(IY + inbp + o);
        *(float4*)(sf + 5 * 1088 + so) = *(const float4*)(IT + inb  + o);
    }
    __syncthreads();

    #pragma unroll
    for (int i = 0; i < 4; ++i) {
        int idx = i * 256 + t; int w = idx >> 4, c = idx & 15;
        int wm = w > 0 ? w - 1 : 0;
        int rb = c * 68;
        float I00 = sf[rb + w],        I0m = sf[rb + wm];
        float Im0 = sf[1088 + rb + w], Imm = sf[1088 + rb + wm];
        float E1  = sf[2176 + rb + w]  - 0.5f * I00;
        float E1m = sf[2176 + rb + wm] - 0.5f * I0m;
        float E2  = sf[3264 + rb + w]  - 0.5f * I00;
        float E2m = sf[4352 + rb + w]  - 0.5f * Im0;
        float v0 = sf[5440 + rb + w];
        float v1 = -E1;
        float v2 = 0.5f * (E1 - E1m);
        float v3 = -E2;
        float v4 = 0.5f * (E2 - E2m);
        float v5 = I00;
        float v6 = 0.5f * (I0m - I00);
        float v7 = 0.5f * (Im0 - I00);
        float v8 = 0.25f * ((Imm - I0m) - (Im0 - I00));
        size_t pt = (((size_t)b * 4096) + (size_t)h * 64 + w) * 64 + (cb + c);
        uint4 o4;
        o4.x = pkh(v0, v1);
        o4.y = pkh(v2, v3);
        o4.z = pkh(v4, v5);
        o4.w = pkh(v6, v7);
        T1[pt] = o4;
        T2[pt] = (ushort)(pkh(v8, 0.f) & 0xffffu);
    }
}

// ---------------------------------------------------------------------------
// k2: fused sampling + rects GEMM + gelu + mask-sum + LN1.  (R5 structure;
// meta expanded in-prologue from slim coords — bit-identical math)
// ---------------------------------------------------------------------------
__global__ __launch_bounds__(256) void k2_rects(
    const uint4* __restrict__ T1, const ushort* __restrict__ T2,
    const float* __restrict__ coords,
    const ushort* __restrict__ w_projP, const float* __restrict__ b_proj,
    const float* __restrict__ maskw, const float* __restrict__ g1,
    const float* __restrict__ beta1, float* __restrict__ mid)
{
    __shared__ __align__(16) uint meta_lds[16][32];
    __shared__ __align__(16) float S_lds[16][68];
    __shared__ float mrow[128];
    __shared__ float outr[2][128];
    int bid = blockIdx.x;
    int b = bid & 7, d = bid >> 3;
    int t = threadIdx.x, w = t >> 6, l = t & 63;
    size_t tile = (size_t)b * DD + d;
    if (t < 64) {
        int u = t >> 2, c = t & 3;
        float4 co = *(const float4*)(coords + (tile * 16 + (size_t)u) * 4);
        float x1 = co.x, y1 = co.y, x2 = co.z, y2 = co.w;
        int X1 = (int)ceilf(x1); X1 = X1 < 1 ? 1 : (X1 > 63 ? 63 : X1);
        int X2 = (int)ceilf(x2); X2 = X2 < 1 ? 1 : (X2 > 63 ? 63 : X2);
        int Y1 = (int)ceilf(y1); Y1 = Y1 < 1 ? 1 : (Y1 > 63 ? 63 : Y1);
        int Y2 = (int)ceilf(y2); Y2 = Y2 < 1 ? 1 : (Y2 > 63 ? 63 : Y2);
        float dxa = (float)X1 - x1, dxb = (float)X2 - x2;
        float dya = (float)Y1 - y1, dyb = (float)Y2 - y2;
        int   Xc = (c & 1) ? X1 : X2;
        int   Yc = (c < 2) ? Y2 : Y1;
        float s  = (c == 0 || c == 3) ? 1.f : -1.f;
        float dx = (c & 1) ? dxa : dxb;
        float dy = (c < 2) ? dyb : dya;
        float dx2 = dx * dx, dy2 = dy * dy;
        uint pt = (uint)(Xc * 64 + Yc);
        uint4 wa, wb;
        wa.x = pt * 1024u;
        wa.y = pt * 128u;
        wa.z = pkh(s, s * dy);
        wa.w = pkh(s * dy2, s * dx);
        wb.x = pkh(s * dx2, s * dx * dy);
        wb.y = pkh(s * dx * dy2, s * dx2 * dy);
        wb.z = __builtin_bit_cast(uint, s * dx2 * dy2);
        wb.w = 0u;
        *(uint4*)&meta_lds[u][c * 8 + 0] = wa;
        *(uint4*)&meta_lds[u][c * 8 + 4] = wb;
    }
    if (t >= 128) mrow[t - 128] = maskw[tile * 128 + (t - 128)];

    bh8 bf[2][2];
    #pragma unroll
    for (int ni = 0; ni < 2; ++ni) {
        int nt = w * 2 + ni;
        #pragma unroll
        for (int ks = 0; ks < 2; ++ks)
            bf[ni][ks] = *(const bh8*)(w_projP + ((size_t)(nt * 2 + ks) * 64 + l) * 8);
    }
    __syncthreads();
    const char* t1b = ((const char*)T1) + ((size_t)b << 22) + (size_t)(l * 16);
    const char* t2b = ((const char*)T2) + ((size_t)b << 19) + (size_t)(l * 2);

    int m0 = w * 4;
    uint4 q[2][4]; ushort e8[2][4];
    #pragma unroll
    for (int g = 0; g < 2; ++g) {
        #pragma unroll
        for (int c = 0; c < 4; ++c) {
            uint o1 = __builtin_amdgcn_readfirstlane(meta_lds[m0 + g][c * 8 + 0]);
            uint o2 = __builtin_amdgcn_readfirstlane(meta_lds[m0 + g][c * 8 + 1]);
            q[g][c]  = *(const uint4*)(t1b + o1);
            e8[g][c] = *(const ushort*)(t2b + o2);
        }
    }
    #pragma unroll
    for (int rr = 0; rr < 4; ++rr) {
        int m = m0 + rr;
        int cur = rr & 1;
        uint4 qc[4]; ushort ec[4];
        #pragma unroll
        for (int c = 0; c < 4; ++c) { qc[c] = q[cur][c]; ec[c] = e8[cur][c]; }
        if (rr < 2) {
            int mn = m + 2;
            #pragma unroll
            for (int c = 0; c < 4; ++c) {
                uint o1 = __builtin_amdgcn_readfirstlane(meta_lds[mn][c * 8 + 0]);
                uint o2 = __builtin_amdgcn_readfirstlane(meta_lds[mn][c * 8 + 1]);
                q[cur][c]  = *(const uint4*)(t1b + o1);
                e8[cur][c] = *(const ushort*)(t2b + o2);
            }
        }
        float acc0 = 0.f, acc1 = 0.f;
        #pragma unroll
        for (int c = 0; c < 4; ++c) {
            uint cz = meta_lds[m][c * 8 + 2], cw = meta_lds[m][c * 8 + 3];
            uint bx = meta_lds[m][c * 8 + 4], by = meta_lds[m][c * 8 + 5];
            float bz = asf(meta_lds[m][c * 8 + 6]);
            float ev = __half2float(__builtin_bit_cast(__half, ec[c]));
            float cv = bz * ev;
            cv = fdot2h(ash2f(by), ash2f(qc[c].w), cv);
            cv = fdot2h(ash2f(bx), ash2f(qc[c].z), cv);
            cv = fdot2h(ash2f(cw), ash2f(qc[c].y), cv);
            cv = fdot2h(ash2f(cz), ash2f(qc[c].x), cv);
            if (c & 1) acc1 += cv; else acc0 += cv;
        }
        S_lds[m][l] = acc0 + acc1;
    }
    __syncthreads();

    int am = l & 15, q2 = l >> 4;
    bh8 a0, a1;
    {
        float4 va = *(const float4*)&S_lds[am][q2 * 8];
        float4 vb = *(const float4*)&S_lds[am][q2 * 8 + 4];
        uint4 ua;
        ua.x = cvtpk_bf16(va.x, va.y);
        ua.y = cvtpk_bf16(va.z, va.w);
        ua.z = cvtpk_bf16(vb.x, vb.y);
        ua.w = cvtpk_bf16(vb.z, vb.w);
        a0 = __builtin_bit_cast(bh8, ua);
        float4 vc = *(const float4*)&S_lds[am][32 + q2 * 8];
        float4 vd = *(const float4*)&S_lds[am][32 + q2 * 8 + 4];
        uint4 ub;
        ub.x = cvtpk_bf16(vc.x, vc.y);
        ub.y = cvtpk_bf16(vc.z, vc.w);
        ub.z = cvtpk_bf16(vd.x, vd.y);
        ub.w = cvtpk_bf16(vd.z, vd.w);
        a1 = __builtin_bit_cast(bh8, ub);
    }
    f32x4 cc[2];
    cc[0] = (f32x4){0.f, 0.f, 0.f, 0.f};
    cc[1] = (f32x4){0.f, 0.f, 0.f, 0.f};
    cc[0] = __builtin_amdgcn_mfma_f32_16x16x32_bf16(a0, bf[0][0], cc[0], 0, 0, 0);
    cc[0] = __builtin_amdgcn_mfma_f32_16x16x32_bf16(a1, bf[0][1], cc[0], 0, 0, 0);
    cc[1] = __builtin_amdgcn_mfma_f32_16x16x32_bf16(a0, bf[1][0], cc[1], 0, 0, 0);
    cc[1] = __builtin_amdgcn_mfma_f32_16x16x32_bf16(a1, bf[1][1], cc[1], 0, 0, 0);

    int cl = l & 15;
    #pragma unroll
    for (int ni = 0; ni < 2; ++ni) {
        int nt = w * 2 + ni;
        int col = nt * 16 + cl;
        float bpv = b_proj[col];
        float p = 0.f;
        #pragma unroll
        for (int reg = 0; reg < 4; ++reg) {
            int r = q2 * 4 + reg;
            float v = cc[ni][reg] + bpv;
            p += gelu_fast(v) * mrow[(r >> 3) * 64 + (r & 7) * 8 + nt];
        }
        p += __shfl_xor(p, 16, 64);
        if (q2 == 0) outr[0][col] = p;
        else if (q2 == 2) outr[1][col] = p;
    }
    __syncthreads();

    if (w < 2) {
        float v0 = outr[w][l], v1 = outr[w][l + 64];
        float s = v0 + v1, sq = v0 * v0 + v1 * v1;
        #pragma unroll
        for (int mm = 32; mm > 0; mm >>= 1) {
            s  += __shfl_xor(s, mm, 64);
            sq += __shfl_xor(sq, mm, 64);
        }
        float mu  = s * (1.0f / 128.0f);
        float var = sq * (1.0f / 128.0f) - mu * mu;
        float rs  = rsqrtf(var + 1e-5f);
        size_t ob = (tile * 2 + w) * 128;
        mid[ob + l]      = (v0 - mu) * rs * g1[l]      + beta1[l];
        mid[ob + l + 64] = (v1 - mu) * rs * g1[l + 64] + beta1[l + 64];
    }
}

// ---------------------------------------------------------------------------
// k4: MLP 128->512(gelu)->128 via MFMA, 16 rows/block, + LN2 + residual.
// ---------------------------------------------------------------------------
__global__ __launch_bounds__(256) void k4_mlp(
    const float* __restrict__ mid, const ushort* __restrict__ w1P,
    const float* __restrict__ b1, const ushort* __restrict__ w2P,
    const float* __restrict__ b2, const float* __restrict__ g2,
    const float* __restrict__ beta2, float* __restrict__ outp)
{
    __shared__ float xr[16][132];
    __shared__ __align__(16) ushort Af[4][64][8];
    __shared__ __align__(16) ushort H[16][520];
    __shared__ float oo[16][128];
    __shared__ float b1s[512];
    __shared__ float b2s[128], g2s[128], bt2s[128];
    int t = threadIdx.x, w = t >> 6, l = t & 63;
    int bid = blockIdx.x;
    int mt = (bid & 7) * 128 + (bid >> 3);   // XCD-local by batch
    size_t rowbase = (size_t)mt * 16;

    {
        const float4* mg = (const float4*)(mid + rowbase * 128);
        #pragma unroll
        for (int i4 = 0; i4 < 2; ++i4) {
            int i = i4 * 256 + t;
            float4 v = mg[i];
            *(float4*)(&xr[i >> 5][(i & 31) * 4]) = v;
        }
    }
    for (int i = t; i < 512; i += 256) b1s[i] = b1[i];
    if (t < 128) { b2s[t] = b2[t]; g2s[t] = g2[t]; bt2s[t] = beta2[t]; }
    __syncthreads();

    {
        int ks = t >> 6, m = l & 15, c0 = ks * 32 + (l >> 4) * 8;
        uint* dst = (uint*)&Af[ks][l][0];
        #pragma unroll
        for (int j = 0; j < 4; ++j)
            dst[j] = cvtpk_bf16(xr[m][c0 + 2 * j], xr[m][c0 + 2 * j + 1]);
    }
    __syncthreads();

    f32x4 c1[8];
    #pragma unroll
    for (int i = 0; i < 8; ++i) c1[i] = (f32x4){0.f, 0.f, 0.f, 0.f};
    bh8 a[4];
    #pragma unroll
    for (int ks = 0; ks < 4; ++ks) a[ks] = *(const bh8*)&Af[ks][l][0];
    #pragma unroll
    for (int ni = 0; ni < 8; ++ni) {
        int nt = w * 8 + ni;
        #pragma unroll
        for (int ks = 0; ks < 4; ++ks) {
            bh8 bfr = *(const bh8*)(w1P + ((size_t)(nt * 4 + ks) * 64 + l) * 8);
            c1[ni] = __builtin_amdgcn_mfma_f32_16x16x32_bf16(a[ks], bfr, c1[ni], 0, 0, 0);
        }
    }
    #pragma unroll
    for (int ni = 0; ni < 8; ++ni) {
        int nt = w * 8 + ni;
        int col = nt * 16 + (l & 15);
        int r0 = (l >> 4) * 4;
        #pragma unroll
        for (int reg = 0; reg < 4; ++reg)
            H[r0 + reg][col] = cvt1_bf16(gelu_fast(c1[ni][reg] + b1s[col]));
    }
    __syncthreads();

    f32x4 c2[2];
    c2[0] = (f32x4){0.f, 0.f, 0.f, 0.f};
    c2[1] = (f32x4){0.f, 0.f, 0.f, 0.f};
    const char* hb = (const char*)&H[0][0];
    #pragma unroll
    for (int ks2 = 0; ks2 < 16; ++ks2) {
        bh8 af = *(const bh8*)(hb + (l & 15) * 1040 + ks2 * 64 + (l >> 4) * 16);
        #pragma unroll
        for (int i = 0; i < 2; ++i) {
            int nt2 = w * 2 + i;
            bh8 bfr = *(const bh8*)(w2P + ((size_t)(nt2 * 16 + ks2) * 64 + l) * 8);
            c2[i] = __builtin_amdgcn_mfma_f32_16x16x32_bf16(af, bfr, c2[i], 0, 0, 0);
        }
    }
    #pragma unroll
    for (int i = 0; i < 2; ++i) {
        int col = (w * 2 + i) * 16 + (l & 15);
        int r0 = (l >> 4) * 4;
        #pragma unroll
        for (int reg = 0; reg < 4; ++reg) oo[r0 + reg][col] = c2[i][reg] + b2s[col];
    }
    __syncthreads();

    #pragma unroll
    for (int rr = 0; rr < 4; ++rr) {
        int r = w * 4 + rr;
        float v0 = oo[r][l], v1 = oo[r][l + 64];
        float s = v0 + v1, sq = v0 * v0 + v1 * v1;
        #pragma unroll
        for (int m = 32; m > 0; m >>= 1) {
            s  += __shfl_xor(s, m, 64);
            sq += __shfl_xor(sq, m, 64);
        }
        float mu  = s * (1.0f / 128.0f);
        float var = sq * (1.0f / 128.0f) - mu * mu;
        float rs  = rsqrtf(var + 1e-5f);
        size_t ob = (rowbase + r) * 128;
        outp[ob + l]      = (v0 - mu) * rs * g2s[l]      + bt2s[l]      + xr[r][l];
        outp[ob + l + 64] = (v1 - mu) * rs * g2s[l + 64] + bt2s[l + 64] + xr[r][l + 64];
    }
}

// ---------------------------------------------------------------------------
extern "C" void kernel_launch(void* const* d_in, const int* in_sizes, int n_in,
                              void* d_out, int out_size, void* d_ws, size_t ws_size,
                              hipStream_t stream) {
    const float* x      = (const float*)d_in[0];
    const float* I      = (const float*)d_in[1];
    const float* IX     = (const float*)d_in[2];
    const float* IY     = (const float*)d_in[3];
    const float* IT     = (const float*)d_in[4];
    const float* w_idx  = (const float*)d_in[5];
    const float* b_idx  = (const float*)d_in[6];
    const float* w_proj = (const float*)d_in[7];
    const float* b_proj = (const float*)d_in[8];
    const float* w_mask = (const float*)d_in[9];
    const float* b_mask = (const float*)d_in[10];
    const float* g1     = (const float*)d_in[11];
    const float* beta1  = (const float*)d_in[12];
    const float* w_mlp1 = (const float*)d_in[13];
    const float* b_mlp1 = (const float*)d_in[14];
    const float* w_mlp2 = (const float*)d_in[15];
    const float* b_mlp2 = (const float*)d_in[16];
    const float* g2     = (const float*)d_in[17];
    const float* beta2  = (const float*)d_in[18];
    float* out = (float*)d_out;

    float* ws = (float*)d_ws;
    ushort* catPh  = (ushort*)ws;                  // 49152 us -> 24576 f
    ushort* catPm  = (ushort*)(ws + 24576);        // 49152 us -> 49152 f
    ushort* catPl  = (ushort*)(ws + 49152);        // 49152 us -> 73728 f
    ushort* w_projP = (ushort*)(ws + 73728);       // 8192 us  -> 77824
    ushort* w1P     = (ushort*)(ws + 77824);       // 65536 us -> 110592
    ushort* w2P     = (ushort*)(ws + 110592);      // 65536 us -> 143360
    float*  maskw   = ws + 143360;                 // 1048576 f -> 1191936
    float*  coords  = ws + 1191936;                // 524288 f  -> 1716224
    uint4*  T1      = (uint4*)(ws + 1716224);      // 2097152 u4 -> 10104832
    ushort* T2      = (ushort*)(ws + 10104832);    // 2097152 us -> 11153408
    unsigned char* rowflag = (unsigned char*)(ws + 11153408);  // 512 B

    kT_pack<<<93, 256, 0, stream>>>(w_idx, w_mask, w_proj, w_mlp1, w_mlp2,
                                    catPh, catPm, catPl, w_projP, w1P, w2P,
                                    (uint*)rowflag);
    kA_coords<<<512, 256, 0, stream>>>(x, catPh, catPm, catPl, b_idx, b_mask,
                                       maskw, coords, rowflag);
    kB_tex<<<2048, 256, 0, stream>>>(I, IX, IY, IT, rowflag, T1, T2);
    k2_rects<<<8192, 256, 0, stream>>>(T1, T2, coords, w_projP, b_proj, maskw,
                                       g1, beta1, out);
    k4_mlp<<<1024, 256, 0, stream>>>(out, w1P, b_mlp1, w2P, b_mlp2, g2, beta2, out);
}

// Round 12
// 78.548 us; speedup vs baseline: 1.2091x; 1.0364x over previous
//
#include <hip/hip_runtime.h>
#include <hip/hip_bf16.h>
#include <hip/hip_fp16.h>
#include <math.h>

#define BB   8
#define DD   1024

typedef short bh8 __attribute__((ext_vector_type(8)));
typedef float f32x4 __attribute__((ext_vector_type(4)));
typedef _Float16 h2f __attribute__((ext_vector_type(2)));

__device__ __forceinline__ ushort f2bf(float f) {
    uint u = __builtin_bit_cast(uint, f);
    u += 0x7fffu + ((u >> 16) & 1u);
    return (ushort)(u >> 16);
}
__device__ __forceinline__ float asf(uint u)  { return __builtin_bit_cast(float, u); }
__device__ __forceinline__ float bflo(uint u) { return __builtin_bit_cast(float, u << 16); }
__device__ __forceinline__ float bfhi(uint u) { return __builtin_bit_cast(float, u & 0xffff0000u); }
__device__ __forceinline__ uint  pkh(float a, float b) {
    return __builtin_bit_cast(uint, __builtin_amdgcn_cvt_pkrtz(a, b));
}
__device__ __forceinline__ h2f ash2f(uint u) { return __builtin_bit_cast(h2f, u); }

#if __has_builtin(__builtin_amdgcn_fdot2)
__device__ __forceinline__ float fdot2h(h2f a, h2f b, float c) {
    return __builtin_amdgcn_fdot2(a, b, c, false);
}
#else
__device__ __forceinline__ float fdot2h(h2f a, h2f b, float c) {
    return fmaf((float)a.x, (float)b.x, fmaf((float)a.y, (float)b.y, c));
}
#endif

// hardware packed f32->bf16 RTNE (no builtin on gfx950; asm per guide recipe)
__device__ __forceinline__ uint cvtpk_bf16(float a, float b) {
    uint r;
    asm("v_cvt_pk_bf16_f32 %0, %1, %2" : "=v"(r) : "v"(a), "v"(b));
    return r;
}
__device__ __forceinline__ ushort cvt1_bf16(float a) {
    uint r;
    asm("v_cvt_pk_bf16_f32 %0, %1, %2" : "=v"(r) : "v"(a), "v"(a));
    return (ushort)r;
}

// overflow-safe tanh-form gelu via exp2 + rcp
__device__ __forceinline__ float gelu_fast(float x) {
    float x2 = x * x;
#if __has_builtin(__builtin_amdgcn_exp2f)
    float e = __builtin_amdgcn_exp2f(x * fmaf(x2, -0.20588652f, -2.3022082f));
#else
    float e = __expf(-(1.5957691216f * x + 0.14270963f * x * x2));
#endif
    return x * __builtin_amdgcn_rcpf(1.0f + e);
}
__device__ __forceinline__ float sig63(float v) {
    return 63.0f * __builtin_amdgcn_rcpf(1.0f + __expf(-v));
}

// ---------------------------------------------------------------------------
// kT: weight preprocessing + rowflag zeroing (bid 92).
// ---------------------------------------------------------------------------
__global__ __launch_bounds__(256) void kT_pack(
    const float* __restrict__ w_idx, const float* __restrict__ w_mask,
    const float* __restrict__ w_proj, const float* __restrict__ w1,
    const float* __restrict__ w2,
    ushort* __restrict__ catPh, ushort* __restrict__ catPm,
    ushort* __restrict__ catPl,
    ushort* __restrict__ w_projP, ushort* __restrict__ w1P,
    ushort* __restrict__ w2P, uint* __restrict__ rowflag)
{
    int bid = blockIdx.x, t = threadIdx.x;
    if (bid < 24) {
        int gid = bid * 256 + t;                  // [0,6144)
        int l = gid & 63, ks = (gid >> 6) & 7, nt = gid >> 9;
        int n = nt * 16 + (l & 15);
        int kbase = ks * 32 + ((l >> 4) << 3);
        const float* src = (n < 64) ? (w_idx + (size_t)n * 256)
                                    : (w_mask + (size_t)(n - 64) * 256);
        ushort* dh = catPh + (size_t)gid * 8;
        ushort* dm = catPm + (size_t)gid * 8;
        ushort* dl = catPl + (size_t)gid * 8;
        #pragma unroll
        for (int j = 0; j < 8; ++j) {
            float v = src[kbase + j];
            ushort h = f2bf(v);
            float hf = __builtin_bit_cast(float, (uint)h << 16);
            float r1 = v - hf;
            ushort m = f2bf(r1); float mf = __builtin_bit_cast(float, (uint)m << 16);
            ushort lo = f2bf(r1 - mf);
            dh[j] = h; dm[j] = m; dl[j] = lo;
        }
    } else if (bid < 28) {               // w_proj (128,64): B[k=c][n=dch]
        int g = (bid - 24) * 256 + t;    // [0,1024)
        int nt = g >> 7, ks = (g >> 6) & 1, l = g & 63;
        int n = nt * 16 + (l & 15), k0 = ks * 32 + (l >> 4) * 8;
        ushort* dst = w_projP + (size_t)g * 8;
        #pragma unroll
        for (int j = 0; j < 8; ++j) dst[j] = f2bf(w_proj[n * 64 + k0 + j]);
    } else if (bid < 60) {               // w_mlp1 (512,128): B[k][n]
        int g = (bid - 28) * 256 + t;    // [0,8192)
        int nt = g >> 8, ks = (g >> 6) & 3, l = g & 63;
        int n = nt * 16 + (l & 15), k0 = ks * 32 + (l >> 4) * 8;
        ushort* dst = w1P + (size_t)g * 8;
        #pragma unroll
        for (int j = 0; j < 8; ++j) dst[j] = f2bf(w1[n * 128 + k0 + j]);
    } else if (bid < 92) {               // w_mlp2 (128,512): B[k][n]
        int g = (bid - 60) * 256 + t;    // [0,8192)
        int nt = g >> 10, ks = (g >> 6) & 15, l = g & 63;
        int n = nt * 16 + (l & 15), k0 = ks * 32 + (l >> 4) * 8;
        ushort* dst = w2P + (size_t)g * 8;
        #pragma unroll
        for (int j = 0; j < 8; ++j) dst[j] = f2bf(w2[n * 512 + k0 + j]);
    } else {                             // zero rowflag (8*64 bytes)
        if (t < 128) rowflag[t] = 0u;
    }
}

// ---------------------------------------------------------------------------
// kA: k0 coords+mask via MFMA (3-way bf16 split), 512 blocks.
// bid = j*8 + b  ->  batch b pinned to XCD b (bid%8==b): coords/maskw land
// in the same XCD L2 that k2 (also b = bid&7) reads them from.
// ---------------------------------------------------------------------------
__global__ __launch_bounds__(256) void kA_coords(
    const float* __restrict__ x,
    const ushort* __restrict__ catPh, const ushort* __restrict__ catPm,
    const ushort* __restrict__ catPl,
    const float* __restrict__ b_idx, const float* __restrict__ b_mask,
    float* __restrict__ maskw, float* __restrict__ coords,
    unsigned char* __restrict__ rowflag)
{
    __shared__ __align__(16) float sOut[16 * 193];
    int t = threadIdx.x;
    int bb8 = blockIdx.x & 7, jj = blockIdx.x >> 3;
    size_t rowbase = ((size_t)bb8 * 64 + (size_t)jj) * 16;
    int w = t >> 6, l = t & 63;

    f32x4 acc[3];
    acc[0] = (f32x4){0.f,0.f,0.f,0.f};
    acc[1] = (f32x4){0.f,0.f,0.f,0.f};
    acc[2] = (f32x4){0.f,0.f,0.f,0.f};
    const float* xr = x + (rowbase + (size_t)(l & 15)) * 256 + ((l >> 4) << 3);

    #pragma unroll
    for (int half = 0; half < 2; ++half) {
        bh8 Ah[4], Am[4], Al[4];
        #pragma unroll
        for (int k4 = 0; k4 < 4; ++k4) {
            int ks = half * 4 + k4;
            float4 v0 = *(const float4*)(xr + ks * 32);
            float4 v1 = *(const float4*)(xr + ks * 32 + 4);
            uint4 uh, um, ul;
            uh.x = cvtpk_bf16(v0.x, v0.y);
            uh.y = cvtpk_bf16(v0.z, v0.w);
            uh.z = cvtpk_bf16(v1.x, v1.y);
            uh.w = cvtpk_bf16(v1.z, v1.w);
            float r0a = v0.x - bflo(uh.x), r0b = v0.y - bfhi(uh.x);
            float r0c = v0.z - bflo(uh.y), r0d = v0.w - bfhi(uh.y);
            float r1a = v1.x - bflo(uh.z), r1b = v1.y - bfhi(uh.z);
            float r1c = v1.z - bflo(uh.w), r1d = v1.w - bfhi(uh.w);
            um.x = cvtpk_bf16(r0a, r0b);
            um.y = cvtpk_bf16(r0c, r0d);
            um.z = cvtpk_bf16(r1a, r1b);
            um.w = cvtpk_bf16(r1c, r1d);
            ul.x = cvtpk_bf16(r0a - bflo(um.x), r0b - bfhi(um.x));
            ul.y = cvtpk_bf16(r0c - bflo(um.y), r0d - bfhi(um.y));
            ul.z = cvtpk_bf16(r1a - bflo(um.z), r1b - bfhi(um.z));
            ul.w = cvtpk_bf16(r1c - bflo(um.w), r1d - bfhi(um.w));
            Ah[k4] = __builtin_bit_cast(bh8, uh);
            Am[k4] = __builtin_bit_cast(bh8, um);
            Al[k4] = __builtin_bit_cast(bh8, ul);
        }
        #pragma unroll
        for (int ntl = 0; ntl < 3; ++ntl) {
            int nt = w * 3 + ntl;
            #pragma unroll
            for (int k4 = 0; k4 < 4; ++k4) {
                int ks = half * 4 + k4;
                size_t fo = ((size_t)(nt * 8 + ks) * 64 + l) * 8;
                bh8 bh = *(const bh8*)(catPh + fo);
                bh8 bm = *(const bh8*)(catPm + fo);
                bh8 bl = *(const bh8*)(catPl + fo);
                acc[ntl] = __builtin_amdgcn_mfma_f32_16x16x32_bf16(Ah[k4], bh, acc[ntl], 0, 0, 0);
                acc[ntl] = __builtin_amdgcn_mfma_f32_16x16x32_bf16(Ah[k4], bm, acc[ntl], 0, 0, 0);
                acc[ntl] = __builtin_amdgcn_mfma_f32_16x16x32_bf16(Am[k4], bh, acc[ntl], 0, 0, 0);
                acc[ntl] = __builtin_amdgcn_mfma_f32_16x16x32_bf16(Ah[k4], bl, acc[ntl], 0, 0, 0);
                acc[ntl] = __builtin_amdgcn_mfma_f32_16x16x32_bf16(Al[k4], bh, acc[ntl], 0, 0, 0);
                acc[ntl] = __builtin_amdgcn_mfma_f32_16x16x32_bf16(Am[k4], bm, acc[ntl], 0, 0, 0);
            }
        }
    }
    {
        int r0 = (l >> 4) * 4, cbase = w * 48 + (l & 15);
        #pragma unroll
        for (int ntl = 0; ntl < 3; ++ntl)
            #pragma unroll
            for (int reg = 0; reg < 4; ++reg)
                sOut[(r0 + reg) * 193 + cbase + ntl * 16] = acc[ntl][reg];
    }
    __syncthreads();

    // coords epilogue + row flags: 16 rows x 16 units = 256 threads
    {
        int row = t >> 4, u = t & 15;
        const float* so = sOut + row * 193;
        int br = u >> 3, nr = u & 7;
        int c0 = br * 32 + nr * 4;
        float4 co;
        co.x = sig63(so[c0 + 0] + b_idx[c0 + 0]);
        co.y = sig63(so[c0 + 1] + b_idx[c0 + 1]);
        co.z = sig63(so[c0 + 2] + b_idx[c0 + 2]);
        co.w = sig63(so[c0 + 3] + b_idx[c0 + 3]);
        size_t tile = rowbase + row;
        *(float4*)(coords + (tile * 16 + (size_t)u) * 4) = co;
        // flag texture rows X1, X2 for this batch (idempotent byte stores)
        int bb = (int)(tile >> 10);
        int Xa = (int)ceilf(co.x); Xa = Xa < 1 ? 1 : (Xa > 63 ? 63 : Xa);
        int Xb = (int)ceilf(co.z); Xb = Xb < 1 ? 1 : (Xb > 63 ? 63 : Xb);
        rowflag[bb * 64 + Xa] = 1;
        rowflag[bb * 64 + Xb] = 1;
    }
    // softmax epilogue: 16 rows x (2 br x 8 g) = 256 threads
    {
        int row = t >> 4, br = (t >> 3) & 1, g = t & 7;
        const float* so = sOut + row * 193 + 64;
        float lg[8];
        float mx = -1e30f;
        #pragma unroll
        for (int nr = 0; nr < 8; ++nr) {
            int idx = br * 64 + nr * 8 + g;
            lg[nr] = so[idx] + b_mask[idx];
            mx = fmaxf(mx, lg[nr]);
        }
        float s = 0.f;
        #pragma unroll
        for (int nr = 0; nr < 8; ++nr) { lg[nr] = __expf(lg[nr] - mx); s += lg[nr]; }
        float inv = __builtin_amdgcn_rcpf(s);
        #pragma unroll
        for (int nr = 0; nr < 8; ++nr)
            maskw[(rowbase + row) * 128 + br * 64 + nr * 8 + g] = lg[nr] * inv;
    }
}

// ---------------------------------------------------------------------------
// kB: 9-coeff texture, 16 channels/block — only for FLAGGED rows.
// bid = (h*4+chunk)*8 + b  ->  batch b pinned to XCD b, so T1/T2 writes
// stay in the SAME XCD L2 that k2's batch-b gathers read from.
// ---------------------------------------------------------------------------
__global__ __launch_bounds__(256) void kB_tex(
    const float* __restrict__ I, const float* __restrict__ IX,
    const float* __restrict__ IY, const float* __restrict__ IT,
    const unsigned char* __restrict__ rowflag,
    uint4* __restrict__ T1, ushort* __restrict__ T2)
{
    __shared__ __align__(16) float sf[6528];
    int t = threadIdx.x;
    int bid = blockIdx.x;
    int b = bid & 7, r = bid >> 3;
    int chunk = r & 3, h = r >> 2;
    if (rowflag[b * 64 + h] == 0) return;

    int hp = h > 0 ? h - 1 : 0;
    int cb = chunk * 16;
    size_t inb  = (size_t)b * 262144 + (size_t)h  * 64;
    size_t inbp = (size_t)b * 262144 + (size_t)hp * 64;

    {
        int c = t >> 4, w4 = (t & 15) << 2;
        size_t o = (size_t)(cb + c) * 4096 + w4;
        int so = c * 68 + w4;
        *(float4*)(sf + 0 * 1088 + so) = *(const float4*)(I  + inb  + o);
        *(float4*)(sf + 1 * 1088 + so) = *(const float4*)(I  + inbp + o);
        *(float4*)(sf + 2 * 1088 + so) = *(const float4*)(IX + inb  + o);
        *(float4*)(sf + 3 * 1088 + so) = *(const float4*)(IY + inb  + o);
        *(float4*)(sf + 4 * 1088 + so) = *(const float4*)(IY + inbp + o);
        *(float4*)(sf + 5 * 1088 + so) = *(const float4*)(IT + inb  + o);
    }
    __syncthreads();

    #pragma unroll
    for (int i = 0; i < 4; ++i) {
        int idx = i * 256 + t; int w = idx >> 4, c = idx & 15;
        int wm = w > 0 ? w - 1 : 0;
        int rb = c * 68;
        float I00 = sf[rb + w],        I0m = sf[rb + wm];
        float Im0 = sf[1088 + rb + w], Imm = sf[1088 + rb + wm];
        float E1  = sf[2176 + rb + w]  - 0.5f * I00;
        float E1m = sf[2176 + rb + wm] - 0.5f * I0m;
        float E2  = sf[3264 + rb + w]  - 0.5f * I00;
        float E2m = sf[4352 + rb + w]  - 0.5f * Im0;
        float v0 = sf[5440 + rb + w];
        float v1 = -E1;
        float v2 = 0.5f * (E1 - E1m);
        float v3 = -E2;
        float v4 = 0.5f * (E2 - E2m);
        float v5 = I00;
        float v6 = 0.5f * (I0m - I00);
        float v7 = 0.5f * (Im0 - I00);
        float v8 = 0.25f * ((Imm - I0m) - (Im0 - I00));
        size_t pt = (((size_t)b * 4096) + (size_t)h * 64 + w) * 64 + (cb + c);
        uint4 o4;
        o4.x = pkh(v0, v1);
        o4.y = pkh(v2, v3);
        o4.z = pkh(v4, v5);
        o4.w = pkh(v6, v7);
        T1[pt] = o4;
        T2[pt] = (ushort)(pkh(v8, 0.f) & 0xffffu);
    }
}

// ---------------------------------------------------------------------------
// k2: fused sampling + rects GEMM + gelu + mask-sum + LN1.  (R5 structure;
// meta expanded in-prologue from slim coords — bit-identical math)
// ---------------------------------------------------------------------------
__global__ __launch_bounds__(256) void k2_rects(
    const uint4* __restrict__ T1, const ushort* __restrict__ T2,
    const float* __restrict__ coords,
    const ushort* __restrict__ w_projP, const float* __restrict__ b_proj,
    const float* __restrict__ maskw, const float* __restrict__ g1,
    const float* __restrict__ beta1, float* __restrict__ mid)
{
    __shared__ __align__(16) uint meta_lds[16][32];
    __shared__ __align__(16) float S_lds[16][68];
    __shared__ float mrow[128];
    __shared__ float outr[2][128];
    int bid = blockIdx.x;
    int b = bid & 7, d = bid >> 3;
    int t = threadIdx.x, w = t >> 6, l = t & 63;
    size_t tile = (size_t)b * DD + d;
    if (t < 64) {
        int u = t >> 2, c = t & 3;
        float4 co = *(const float4*)(coords + (tile * 16 + (size_t)u) * 4);
        float x1 = co.x, y1 = co.y, x2 = co.z, y2 = co.w;
        int X1 = (int)ceilf(x1); X1 = X1 < 1 ? 1 : (X1 > 63 ? 63 : X1);
        int X2 = (int)ceilf(x2); X2 = X2 < 1 ? 1 : (X2 > 63 ? 63 : X2);
        int Y1 = (int)ceilf(y1); Y1 = Y1 < 1 ? 1 : (Y1 > 63 ? 63 : Y1);
        int Y2 = (int)ceilf(y2); Y2 = Y2 < 1 ? 1 : (Y2 > 63 ? 63 : Y2);
        float dxa = (float)X1 - x1, dxb = (float)X2 - x2;
        float dya = (float)Y1 - y1, dyb = (float)Y2 - y2;
        int   Xc = (c & 1) ? X1 : X2;
        int   Yc = (c < 2) ? Y2 : Y1;
        float s  = (c == 0 || c == 3) ? 1.f : -1.f;
        float dx = (c & 1) ? dxa : dxb;
        float dy = (c < 2) ? dyb : dya;
        float dx2 = dx * dx, dy2 = dy * dy;
        uint pt = (uint)(Xc * 64 + Yc);
        uint4 wa, wb;
        wa.x = pt * 1024u;
        wa.y = pt * 128u;
        wa.z = pkh(s, s * dy);
        wa.w = pkh(s * dy2, s * dx);
        wb.x = pkh(s * dx2, s * dx * dy);
        wb.y = pkh(s * dx * dy2, s * dx2 * dy);
        wb.z = __builtin_bit_cast(uint, s * dx2 * dy2);
        wb.w = 0u;
        *(uint4*)&meta_lds[u][c * 8 + 0] = wa;
        *(uint4*)&meta_lds[u][c * 8 + 4] = wb;
    }
    if (t >= 128) mrow[t - 128] = maskw[tile * 128 + (t - 128)];

    bh8 bf[2][2];
    #pragma unroll
    for (int ni = 0; ni < 2; ++ni) {
        int nt = w * 2 + ni;
        #pragma unroll
        for (int ks = 0; ks < 2; ++ks)
            bf[ni][ks] = *(const bh8*)(w_projP + ((size_t)(nt * 2 + ks) * 64 + l) * 8);
    }
    __syncthreads();
    const char* t1b = ((const char*)T1) + ((size_t)b << 22) + (size_t)(l * 16);
    const char* t2b = ((const char*)T2) + ((size_t)b << 19) + (size_t)(l * 2);

    int m0 = w * 4;
    uint4 q[2][4]; ushort e8[2][4];
    #pragma unroll
    for (int g = 0; g < 2; ++g) {
        #pragma unroll
        for (int c = 0; c < 4; ++c) {
            uint o1 = __builtin_amdgcn_readfirstlane(meta_lds[m0 + g][c * 8 + 0]);
            uint o2 = __builtin_amdgcn_readfirstlane(meta_lds[m0 + g][c * 8 + 1]);
            q[g][c]  = *(const uint4*)(t1b + o1);
            e8[g][c] = *(const ushort*)(t2b + o2);
        }
    }
    #pragma unroll
    for (int rr = 0; rr < 4; ++rr) {
        int m = m0 + rr;
        int cur = rr & 1;
        uint4 qc[4]; ushort ec[4];
        #pragma unroll
        for (int c = 0; c < 4; ++c) { qc[c] = q[cur][c]; ec[c] = e8[cur][c]; }
        if (rr < 2) {
            int mn = m + 2;
            #pragma unroll
            for (int c = 0; c < 4; ++c) {
                uint o1 = __builtin_amdgcn_readfirstlane(meta_lds[mn][c * 8 + 0]);
                uint o2 = __builtin_amdgcn_readfirstlane(meta_lds[mn][c * 8 + 1]);
                q[cur][c]  = *(const uint4*)(t1b + o1);
                e8[cur][c] = *(const ushort*)(t2b + o2);
            }
        }
        float acc0 = 0.f, acc1 = 0.f;
        #pragma unroll
        for (int c = 0; c < 4; ++c) {
            uint cz = meta_lds[m][c * 8 + 2], cw = meta_lds[m][c * 8 + 3];
            uint bx = meta_lds[m][c * 8 + 4], by = meta_lds[m][c * 8 + 5];
            float bz = asf(meta_lds[m][c * 8 + 6]);
            float ev = __half2float(__builtin_bit_cast(__half, ec[c]));
            float cv = bz * ev;
            cv = fdot2h(ash2f(by), ash2f(qc[c].w), cv);
            cv = fdot2h(ash2f(bx), ash2f(qc[c].z), cv);
            cv = fdot2h(ash2f(cw), ash2f(qc[c].y), cv);
            cv = fdot2h(ash2f(cz), ash2f(qc[c].x), cv);
            if (c & 1) acc1 += cv; else acc0 += cv;
        }
        S_lds[m][l] = acc0 + acc1;
    }
    __syncthreads();

    int am = l & 15, q2 = l >> 4;
    bh8 a0, a1;
    {
        float4 va = *(const float4*)&S_lds[am][q2 * 8];
        float4 vb = *(const float4*)&S_lds[am][q2 * 8 + 4];
        uint4 ua;
        ua.x = cvtpk_bf16(va.x, va.y);
        ua.y = cvtpk_bf16(va.z, va.w);
        ua.z = cvtpk_bf16(vb.x, vb.y);
        ua.w = cvtpk_bf16(vb.z, vb.w);
        a0 = __builtin_bit_cast(bh8, ua);
        float4 vc = *(const float4*)&S_lds[am][32 + q2 * 8];
        float4 vd = *(const float4*)&S_lds[am][32 + q2 * 8 + 4];
        uint4 ub;
        ub.x = cvtpk_bf16(vc.x, vc.y);
        ub.y = cvtpk_bf16(vc.z, vc.w);
        ub.z = cvtpk_bf16(vd.x, vd.y);
        ub.w = cvtpk_bf16(vd.z, vd.w);
        a1 = __builtin_bit_cast(bh8, ub);
    }
    f32x4 cc[2];
    cc[0] = (f32x4){0.f, 0.f, 0.f, 0.f};
    cc[1] = (f32x4){0.f, 0.f, 0.f, 0.f};
    cc[0] = __builtin_amdgcn_mfma_f32_16x16x32_bf16(a0, bf[0][0], cc[0], 0, 0, 0);
    cc[0] = __builtin_amdgcn_mfma_f32_16x16x32_bf16(a1, bf[0][1], cc[0], 0, 0, 0);
    cc[1] = __builtin_amdgcn_mfma_f32_16x16x32_bf16(a0, bf[1][0], cc[1], 0, 0, 0);
    cc[1] = __builtin_amdgcn_mfma_f32_16x16x32_bf16(a1, bf[1][1], cc[1], 0, 0, 0);

    int cl = l & 15;
    #pragma unroll
    for (int ni = 0; ni < 2; ++ni) {
        int nt = w * 2 + ni;
        int col = nt * 16 + cl;
        float bpv = b_proj[col];
        float p = 0.f;
        #pragma unroll
        for (int reg = 0; reg < 4; ++reg) {
            int r = q2 * 4 + reg;
            float v = cc[ni][reg] + bpv;
            p += gelu_fast(v) * mrow[(r >> 3) * 64 + (r & 7) * 8 + nt];
        }
        p += __shfl_xor(p, 16, 64);
        if (q2 == 0) outr[0][col] = p;
        else if (q2 == 2) outr[1][col] = p;
    }
    __syncthreads();

    if (w < 2) {
        float v0 = outr[w][l], v1 = outr[w][l + 64];
        float s = v0 + v1, sq = v0 * v0 + v1 * v1;
        #pragma unroll
        for (int mm = 32; mm > 0; mm >>= 1) {
            s  += __shfl_xor(s, mm, 64);
            sq += __shfl_xor(sq, mm, 64);
        }
        float mu  = s * (1.0f / 128.0f);
        float var = sq * (1.0f / 128.0f) - mu * mu;
        float rs  = rsqrtf(var + 1e-5f);
        size_t ob = (tile * 2 + w) * 128;
        mid[ob + l]      = (v0 - mu) * rs * g1[l]      + beta1[l];
        mid[ob + l + 64] = (v1 - mu) * rs * g1[l + 64] + beta1[l + 64];
    }
}

// ---------------------------------------------------------------------------
// k4: MLP 128->512(gelu)->128 via MFMA, 16 rows/block, + LN2 + residual.
// ---------------------------------------------------------------------------
__global__ __launch_bounds__(256) void k4_mlp(
    const float* __restrict__ mid, const ushort* __restrict__ w1P,
    const float* __restrict__ b1, const ushort* __restrict__ w2P,
    const float* __restrict__ b2, const float* __restrict__ g2,
    const float* __restrict__ beta2, float* __restrict__ outp)
{
    __shared__ float xr[16][132];
    __shared__ __align__(16) ushort Af[4][64][8];
    __shared__ __align__(16) ushort H[16][520];
    __shared__ float oo[16][128];
    __shared__ float b1s[512];
    __shared__ float b2s[128], g2s[128], bt2s[128];
    int t = threadIdx.x, w = t >> 6, l = t & 63;
    int bid = blockIdx.x;
    int mt = (bid & 7) * 128 + (bid >> 3);   // XCD-local by batch
    size_t rowbase = (size_t)mt * 16;

    {
        const float4* mg = (const float4*)(mid + rowbase * 128);
        #pragma unroll
        for (int i4 = 0; i4 < 2; ++i4) {
            int i = i4 * 256 + t;
            float4 v = mg[i];
            *(float4*)(&xr[i >> 5][(i & 31) * 4]) = v;
        }
    }
    for (int i = t; i < 512; i += 256) b1s[i] = b1[i];
    if (t < 128) { b2s[t] = b2[t]; g2s[t] = g2[t]; bt2s[t] = beta2[t]; }
    __syncthreads();

    {
        int ks = t >> 6, m = l & 15, c0 = ks * 32 + (l >> 4) * 8;
        uint* dst = (uint*)&Af[ks][l][0];
        #pragma unroll
        for (int j = 0; j < 4; ++j)
            dst[j] = cvtpk_bf16(xr[m][c0 + 2 * j], xr[m][c0 + 2 * j + 1]);
    }
    __syncthreads();

    f32x4 c1[8];
    #pragma unroll
    for (int i = 0; i < 8; ++i) c1[i] = (f32x4){0.f, 0.f, 0.f, 0.f};
    bh8 a[4];
    #pragma unroll
    for (int ks = 0; ks < 4; ++ks) a[ks] = *(const bh8*)&Af[ks][l][0];
    #pragma unroll
    for (int ni = 0; ni < 8; ++ni) {
        int nt = w * 8 + ni;
        #pragma unroll
        for (int ks = 0; ks < 4; ++ks) {
            bh8 bfr = *(const bh8*)(w1P + ((size_t)(nt * 4 + ks) * 64 + l) * 8);
            c1[ni] = __builtin_amdgcn_mfma_f32_16x16x32_bf16(a[ks], bfr, c1[ni], 0, 0, 0);
        }
    }
    #pragma unroll
    for (int ni = 0; ni < 8; ++ni) {
        int nt = w * 8 + ni;
        int col = nt * 16 + (l & 15);
        int r0 = (l >> 4) * 4;
        #pragma unroll
        for (int reg = 0; reg < 4; ++reg)
            H[r0 + reg][col] = cvt1_bf16(gelu_fast(c1[ni][reg] + b1s[col]));
    }
    __syncthreads();

    f32x4 c2[2];
    c2[0] = (f32x4){0.f, 0.f, 0.f, 0.f};
    c2[1] = (f32x4){0.f, 0.f, 0.f, 0.f};
    const char* hb = (const char*)&H[0][0];
    #pragma unroll
    for (int ks2 = 0; ks2 < 16; ++ks2) {
        bh8 af = *(const bh8*)(hb + (l & 15) * 1040 + ks2 * 64 + (l >> 4) * 16);
        #pragma unroll
        for (int i = 0; i < 2; ++i) {
            int nt2 = w * 2 + i;
            bh8 bfr = *(const bh8*)(w2P + ((size_t)(nt2 * 16 + ks2) * 64 + l) * 8);
            c2[i] = __builtin_amdgcn_mfma_f32_16x16x32_bf16(af, bfr, c2[i], 0, 0, 0);
        }
    }
    #pragma unroll
    for (int i = 0; i < 2; ++i) {
        int col = (w * 2 + i) * 16 + (l & 15);
        int r0 = (l >> 4) * 4;
        #pragma unroll
        for (int reg = 0; reg < 4; ++reg) oo[r0 + reg][col] = c2[i][reg] + b2s[col];
    }
    __syncthreads();

    #pragma unroll
    for (int rr = 0; rr < 4; ++rr) {
        int r = w * 4 + rr;
        float v0 = oo[r][l], v1 = oo[r][l + 64];
        float s = v0 + v1, sq = v0 * v0 + v1 * v1;
        #pragma unroll
        for (int m = 32; m > 0; m >>= 1) {
            s  += __shfl_xor(s, m, 64);
            sq += __shfl_xor(sq, m, 64);
        }
        float mu  = s * (1.0f / 128.0f);
        float var = sq * (1.0f / 128.0f) - mu * mu;
        float rs  = rsqrtf(var + 1e-5f);
        size_t ob = (rowbase + r) * 128;
        outp[ob + l]      = (v0 - mu) * rs * g2s[l]      + bt2s[l]      + xr[r][l];
        outp[ob + l + 64] = (v1 - mu) * rs * g2s[l + 64] + bt2s[l + 64] + xr[r][l + 64];
    }
}

// ---------------------------------------------------------------------------
extern "C" void kernel_launch(void* const* d_in, const int* in_sizes, int n_in,
                              void* d_out, int out_size, void* d_ws, size_t ws_size,
                              hipStream_t stream) {
    const float* x      = (const float*)d_in[0];
    const float* I      = (const float*)d_in[1];
    const float* IX     = (const float*)d_in[2];
    const float* IY     = (const float*)d_in[3];
    const float* IT     = (const float*)d_in[4];
    const float* w_idx  = (const float*)d_in[5];
    const float* b_idx  = (const float*)d_in[6];
    const float* w_proj = (const float*)d_in[7];
    const float* b_proj = (const float*)d_in[8];
    const float* w_mask = (const float*)d_in[9];
    const float* b_mask = (const float*)d_in[10];
    const float* g1     = (const float*)d_in[11];
    const float* beta1  = (const float*)d_in[12];
    const float* w_mlp1 = (const float*)d_in[13];
    const float* b_mlp1 = (const float*)d_in[14];
    const float* w_mlp2 = (const float*)d_in[15];
    const float* b_mlp2 = (const float*)d_in[16];
    const float* g2     = (const float*)d_in[17];
    const float* beta2  = (const float*)d_in[18];
    float* out = (float*)d_out;

    float* ws = (float*)d_ws;
    ushort* catPh  = (ushort*)ws;                  // 49152 us -> 24576 f
    ushort* catPm  = (ushort*)(ws + 24576);        // 49152 us -> 49152 f
    ushort* catPl  = (ushort*)(ws + 49152);        // 49152 us -> 73728 f
    ushort* w_projP = (ushort*)(ws + 73728);       // 8192 us  -> 77824
    ushort* w1P     = (ushort*)(ws + 77824);       // 65536 us -> 110592
    ushort* w2P     = (ushort*)(ws + 110592);      // 65536 us -> 143360
    float*  maskw   = ws + 143360;                 // 1048576 f -> 1191936
    float*  coords  = ws + 1191936;                // 524288 f  -> 1716224
    uint4*  T1      = (uint4*)(ws + 1716224);      // 2097152 u4 -> 10104832
    ushort* T2      = (ushort*)(ws + 10104832);    // 2097152 us -> 11153408
    unsigned char* rowflag = (unsigned char*)(ws + 11153408);  // 512 B

    kT_pack<<<93, 256, 0, stream>>>(w_idx, w_mask, w_proj, w_mlp1, w_mlp2,
                                    catPh, catPm, catPl, w_projP, w1P, w2P,
                                    (uint*)rowflag);
    kA_coords<<<512, 256, 0, stream>>>(x, catPh, catPm, catPl, b_idx, b_mask,
                                       maskw, coords, rowflag);
    kB_tex<<<2048, 256, 0, stream>>>(I, IX, IY, IT, rowflag, T1, T2);
    k2_rects<<<8192, 256, 0, stream>>>(T1, T2, coords, w_projP, b_proj, maskw,
                                       g1, beta1, out);
    k4_mlp<<<1024, 256, 0, stream>>>(out, w1P, b_mlp1, w2P, b_mlp2, g2, beta2, out);
}